// Round 2
// baseline (6370.572 us; speedup 1.0000x reference)
//
#include <hip/hip_runtime.h>
#include <hip/hip_bf16.h>
#include <math.h>

namespace {

constexpr int T = 1024;      // sequence length
constexpr int D = 768;       // model dim
constexpr int FF = 3072;     // ffn dim
constexpr int H = 12;        // heads
constexpr int HD = 64;       // head dim
constexpr int L = 12;        // layers
constexpr float SCALE = 0.125f;                 // 1/sqrt(64)

// ---------------- embedding: h0 = wte[ids] + wpe ----------------
__global__ void embed_kernel(const int* __restrict__ ids,
                             const float* __restrict__ wte,
                             const float* __restrict__ wpe,
                             float* __restrict__ h) {
    int i = blockIdx.x * blockDim.x + threadIdx.x;
    if (i >= T * D) return;
    int t = i / D, d = i % D;
    h[i] = wte[(long)ids[t] * D + d] + wpe[i];
}

// ---------------- layernorm over D=768, one row per block (256 thr) ----------------
__global__ __launch_bounds__(256)
void ln_kernel(const float* __restrict__ x, const float* __restrict__ g,
               const float* __restrict__ b, float* __restrict__ out) {
    int row = blockIdx.x, tid = threadIdx.x;
    const float* xr = x + (long)row * D;
    float v0 = xr[tid], v1 = xr[tid + 256], v2 = xr[tid + 512];
    __shared__ float red[4];
    __shared__ float share;
    float s = v0 + v1 + v2;
#pragma unroll
    for (int o = 32; o; o >>= 1) s += __shfl_down(s, o, 64);
    if ((tid & 63) == 0) red[tid >> 6] = s;
    __syncthreads();
    if (tid == 0) share = (red[0] + red[1] + red[2] + red[3]) * (1.0f / D);
    __syncthreads();
    float mu = share;
    float d0 = v0 - mu, d1 = v1 - mu, d2 = v2 - mu;
    float q = d0 * d0 + d1 * d1 + d2 * d2;
#pragma unroll
    for (int o = 32; o; o >>= 1) q += __shfl_down(q, o, 64);
    __syncthreads();   // protect red reuse
    if ((tid & 63) == 0) red[tid >> 6] = q;
    __syncthreads();
    if (tid == 0) share = rsqrtf((red[0] + red[1] + red[2] + red[3]) * (1.0f / D) + 1e-5f);
    __syncthreads();
    float rs = share;
    float* orow = out + (long)row * D;
    orow[tid]       = d0 * rs * g[tid]       + b[tid];
    orow[tid + 256] = d1 * rs * g[tid + 256] + b[tid + 256];
    orow[tid + 512] = d2 * rs * g[tid + 512] + b[tid + 512];
}

// ---------------- generic fp32 GEMM C = A@B (+bias)(+gelu)(+resid) ----------------
// 64x64 tile, BK=16, 256 threads, 4x4 micro-tile. All dims assumed %64 / %16.
// flags: 1=bias(per col), 2=resid add (ld==ldc), 4=gelu(tanh)
__global__ __launch_bounds__(256)
void gemm_nn(const float* __restrict__ A, const float* __restrict__ B,
             const float* __restrict__ bias, const float* __restrict__ resid,
             float* __restrict__ C,
             int K, int lda, int ldb, int ldc,
             long batchA, long batchB, long batchC, int flags) {
    A += (long)blockIdx.z * batchA;
    B += (long)blockIdx.z * batchB;
    C += (long)blockIdx.z * batchC;
    __shared__ float As[16][65];
    __shared__ float Bs[16][64];
    const int row0 = blockIdx.y * 64, col0 = blockIdx.x * 64;
    const int tid = threadIdx.x;
    const int tx = tid & 15, ty = tid >> 4;
    const int ar = tid >> 2, ac = (tid & 3) * 4;   // A tile load coords
    const int br = tid >> 4, bc = (tid & 15) * 4;  // B tile load coords
    float acc[4][4] = {};
    for (int k0 = 0; k0 < K; k0 += 16) {
        float4 av = *(const float4*)(A + (long)(row0 + ar) * lda + k0 + ac);
        float4 bv = *(const float4*)(B + (long)(k0 + br) * ldb + col0 + bc);
        As[ac + 0][ar] = av.x; As[ac + 1][ar] = av.y;
        As[ac + 2][ar] = av.z; As[ac + 3][ar] = av.w;
        *(float4*)&Bs[br][bc] = bv;
        __syncthreads();
#pragma unroll
        for (int kk = 0; kk < 16; kk++) {
            float a0 = As[kk][ty * 4 + 0], a1 = As[kk][ty * 4 + 1];
            float a2 = As[kk][ty * 4 + 2], a3 = As[kk][ty * 4 + 3];
            float b0 = Bs[kk][tx * 4 + 0], b1 = Bs[kk][tx * 4 + 1];
            float b2 = Bs[kk][tx * 4 + 2], b3 = Bs[kk][tx * 4 + 3];
            acc[0][0] += a0 * b0; acc[0][1] += a0 * b1; acc[0][2] += a0 * b2; acc[0][3] += a0 * b3;
            acc[1][0] += a1 * b0; acc[1][1] += a1 * b1; acc[1][2] += a1 * b2; acc[1][3] += a1 * b3;
            acc[2][0] += a2 * b0; acc[2][1] += a2 * b1; acc[2][2] += a2 * b2; acc[2][3] += a2 * b3;
            acc[3][0] += a3 * b0; acc[3][1] += a3 * b1; acc[3][2] += a3 * b2; acc[3][3] += a3 * b3;
        }
        __syncthreads();
    }
#pragma unroll
    for (int i = 0; i < 4; i++) {
        int r = row0 + ty * 4 + i;
#pragma unroll
        for (int j = 0; j < 4; j++) {
            int c = col0 + tx * 4 + j;
            float v = acc[i][j];
            if (flags & 1) v += bias[c];
            if (flags & 4) {
                v = 0.5f * v * (1.0f + tanhf(0.7978845608028654f * (v + 0.044715f * v * v * v)));
            }
            if (flags & 2) v += resid[(long)r * ldc + c];
            C[(long)r * ldc + c] = v;
        }
    }
}

// ---------------- fused flash attention (fp32, causal), 32 q-rows per block ----------------
// grid (T/32, H), 256 threads. Reads qkv (T x 3D, head-strided), writes ctx (T x D).
__global__ __launch_bounds__(256)
void flash_attn(const float* __restrict__ qkv, float* __restrict__ ctx) {
    const int h = blockIdx.y;
    const int r0 = blockIdx.x * 32;
    const int tid = threadIdx.x;
    const int r = tid & 31;     // local q row (both phases)
    const int g = tid >> 5;     // group 0..7: c-group (scores) / d-group (PV)
    __shared__ float Qs[32][68];   // pad 68: float4-aligned rows
    __shared__ float Ks[32][68];
    __shared__ float Vs[32][68];
    __shared__ float Ps[32][33];
    __shared__ float RedM[32][9];
    __shared__ float RedS[32][9];

    // load Q tile (32 rows x 64)
    for (int idx = tid; idx < 512; idx += 256) {
        int rr = idx >> 4, c4 = (idx & 15) << 2;
        *(float4*)&Qs[rr][c4] =
            *(const float4*)(qkv + (long)(r0 + rr) * (3 * D) + h * HD + c4);
    }
    float m = -INFINITY, l = 0.f;
    float o[8] = {0, 0, 0, 0, 0, 0, 0, 0};
    const int rg = r0 + r;
    const int cbase = g * 4;

    for (int c0 = 0; c0 <= r0; c0 += 32) {
        __syncthreads();   // protect Ks/Vs/Ps/Red from previous-iteration reads
        for (int idx = tid; idx < 512; idx += 256) {
            int rr = idx >> 4, c4 = (idx & 15) << 2;
            const float* src = qkv + (long)(c0 + rr) * (3 * D) + D + h * HD + c4;
            *(float4*)&Ks[rr][c4] = *(const float4*)src;
            *(float4*)&Vs[rr][c4] = *(const float4*)(src + D);
        }
        __syncthreads();
        // scores: this thread computes s[r][cbase..cbase+3]
        float a0 = 0, a1 = 0, a2 = 0, a3 = 0;
#pragma unroll
        for (int d = 0; d < 64; d += 4) {
            float4 q4 = *(const float4*)&Qs[r][d];
            float4 k0 = *(const float4*)&Ks[cbase + 0][d];
            float4 k1 = *(const float4*)&Ks[cbase + 1][d];
            float4 k2 = *(const float4*)&Ks[cbase + 2][d];
            float4 k3 = *(const float4*)&Ks[cbase + 3][d];
            a0 += q4.x * k0.x + q4.y * k0.y + q4.z * k0.z + q4.w * k0.w;
            a1 += q4.x * k1.x + q4.y * k1.y + q4.z * k1.z + q4.w * k1.w;
            a2 += q4.x * k2.x + q4.y * k2.y + q4.z * k2.z + q4.w * k2.w;
            a3 += q4.x * k3.x + q4.y * k3.y + q4.z * k3.z + q4.w * k3.w;
        }
        float s0 = (c0 + cbase + 0 <= rg) ? a0 * SCALE : -INFINITY;
        float s1 = (c0 + cbase + 1 <= rg) ? a1 * SCALE : -INFINITY;
        float s2 = (c0 + cbase + 2 <= rg) ? a2 * SCALE : -INFINITY;
        float s3 = (c0 + cbase + 3 <= rg) ? a3 * SCALE : -INFINITY;
        RedM[r][g] = fmaxf(fmaxf(s0, s1), fmaxf(s2, s3));
        __syncthreads();
        float mn = m;
#pragma unroll
        for (int k = 0; k < 8; k++) mn = fmaxf(mn, RedM[r][k]);
        float alpha = expf(m - mn);   // m=-inf on first tile -> 0
        float p0 = expf(s0 - mn), p1 = expf(s1 - mn);
        float p2 = expf(s2 - mn), p3 = expf(s3 - mn);   // masked -> exp(-inf)=0
        Ps[r][cbase + 0] = p0; Ps[r][cbase + 1] = p1;
        Ps[r][cbase + 2] = p2; Ps[r][cbase + 3] = p3;
        RedS[r][g] = p0 + p1 + p2 + p3;
        __syncthreads();
        float ps = 0;
#pragma unroll
        for (int k = 0; k < 8; k++) ps += RedS[r][k];
        l = l * alpha + ps;
        m = mn;
#pragma unroll
        for (int j = 0; j < 8; j++) o[j] *= alpha;
        // PV: this thread accumulates dims [g*8, g*8+8) of its row
        for (int c = 0; c < 32; c++) {
            float p = Ps[r][c];
            float4 v0 = *(const float4*)&Vs[c][g * 8];
            float4 v1 = *(const float4*)&Vs[c][g * 8 + 4];
            o[0] += p * v0.x; o[1] += p * v0.y; o[2] += p * v0.z; o[3] += p * v0.w;
            o[4] += p * v1.x; o[5] += p * v1.y; o[6] += p * v1.z; o[7] += p * v1.w;
        }
    }
    float inv = 1.0f / l;
    float4 w0 = {o[0] * inv, o[1] * inv, o[2] * inv, o[3] * inv};
    float4 w1 = {o[4] * inv, o[5] * inv, o[6] * inv, o[7] * inv};
    float* dst = ctx + (long)rg * D + h * HD + g * 8;
    *(float4*)dst = w0;
    *(float4*)(dst + 4) = w1;
}

// ---------------- probe: softmax rows S2 and T-1 per head, write 4 outputs ----------------
// grid (2, H): blockIdx.x 0 -> row S2 (dup, ind), 1 -> row T-1 (prev, name)
__global__ __launch_bounds__(256)
void probe_kernel(const float* __restrict__ qkv,
                  const int* __restrict__ Sp, const int* __restrict__ Sa1p,
                  const int* __restrict__ S2p,
                  float* __restrict__ out, int layer) {
    const int h = blockIdx.y;
    const int which = blockIdx.x;
    const int s = *Sp, sa1 = *Sa1p, s2 = *S2p;
    const int row = which ? (T - 1) : s2;
    const int tid = threadIdx.x;
    __shared__ float qrow[64];
    __shared__ float prob[T];
    __shared__ float red[4];
    __shared__ float bshare;
    if (tid < 64) qrow[tid] = qkv[(long)row * (3 * D) + h * HD + tid];
    __syncthreads();
    float mloc = -INFINITY;
    for (int j = tid; j <= row; j += 256) {
        const float* krow = qkv + (long)j * (3 * D) + D + h * HD;
        float acc = 0;
#pragma unroll
        for (int d = 0; d < 64; d += 4) {
            float4 kv = *(const float4*)(krow + d);
            acc += qrow[d] * kv.x + qrow[d + 1] * kv.y +
                   qrow[d + 2] * kv.z + qrow[d + 3] * kv.w;
        }
        acc *= SCALE;
        prob[j] = acc;
        mloc = fmaxf(mloc, acc);
    }
#pragma unroll
    for (int o = 32; o; o >>= 1) mloc = fmaxf(mloc, __shfl_down(mloc, o, 64));
    if ((tid & 63) == 0) red[tid >> 6] = mloc;
    __syncthreads();
    if (tid == 0) bshare = fmaxf(fmaxf(red[0], red[1]), fmaxf(red[2], red[3]));
    __syncthreads();
    float m = bshare;
    float ssum = 0;
    for (int j = tid; j <= row; j += 256) {
        float e = expf(prob[j] - m);
        prob[j] = e;
        ssum += e;
    }
#pragma unroll
    for (int o = 32; o; o >>= 1) ssum += __shfl_down(ssum, o, 64);
    __syncthreads();
    if ((tid & 63) == 0) red[tid >> 6] = ssum;
    __syncthreads();
    if (tid == 0) bshare = red[0] + red[1] + red[2] + red[3];
    __syncthreads();
    float inv = 1.0f / bshare;
    if (tid == 0) {
        if (which == 0) {
            out[0 * (L * H) + layer * H + h] = prob[s] * inv;
            out[1 * (L * H) + layer * H + h] = prob[sa1] * inv;
        } else {
            out[2 * (L * H) + layer * H + h] = prob[s2] * inv;
            out[3 * (L * H) + layer * H + h] = prob[s2] * inv;
        }
    }
}

}  // namespace

extern "C" void kernel_launch(void* const* d_in, const int* in_sizes, int n_in,
                              void* d_out, int out_size, void* d_ws, size_t ws_size,
                              hipStream_t stream) {
    const int*   ids    = (const int*)  d_in[0];
    const float* wte    = (const float*)d_in[2];
    const float* wpe    = (const float*)d_in[3];
    const float* ln1_g  = (const float*)d_in[4];
    const float* ln1_b  = (const float*)d_in[5];
    const float* W_qkv  = (const float*)d_in[6];
    const float* b_qkv  = (const float*)d_in[7];
    const float* W_o    = (const float*)d_in[8];
    const float* b_o    = (const float*)d_in[9];
    const float* ln2_g  = (const float*)d_in[10];
    const float* ln2_b  = (const float*)d_in[11];
    const float* W_fc   = (const float*)d_in[12];
    const float* b_fc   = (const float*)d_in[13];
    const float* W_proj = (const float*)d_in[14];
    const float* b_proj = (const float*)d_in[15];
    const int*   Sp     = (const int*)  d_in[16];
    const int*   Sa1p   = (const int*)  d_in[17];
    const int*   S2p    = (const int*)  d_in[18];
    float* out = (float*)d_out;

    float* ws  = (float*)d_ws;
    float* h   = ws;                     // T*D
    float* xl  = h   + (long)T * D;      // T*D (ln1 and ln2 output)
    float* h2  = xl  + (long)T * D;      // T*D
    float* qkv = h2  + (long)T * D;      // T*3D
    float* ctx = qkv + (long)T * 3 * D;  // T*D
    float* f   = ctx + (long)T * D;      // T*FF

    embed_kernel<<<(T * D + 255) / 256, 256, 0, stream>>>(ids, wte, wpe, h);

    for (int l = 0; l < L; l++) {
        // xl = ln1(h)
        ln_kernel<<<T, 256, 0, stream>>>(h, ln1_g + l * D, ln1_b + l * D, xl);
        // qkv = xl @ W_qkv[l] + b_qkv[l]
        gemm_nn<<<dim3(3 * D / 64, T / 64, 1), 256, 0, stream>>>(
            xl, W_qkv + (long)l * D * 3 * D, b_qkv + (long)l * 3 * D, nullptr, qkv,
            D, D, 3 * D, 3 * D, 0, 0, 0, 1);
        // probe outputs for this layer (needs only qkv)
        probe_kernel<<<dim3(2, H), 256, 0, stream>>>(qkv, Sp, Sa1p, S2p, out, l);

        if (l == L - 1) break;  // last layer: h_new unused

        // ctx = causal-softmax(QK^T*scale) @ V, fused (no score materialization)
        flash_attn<<<dim3(T / 32, H), 256, 0, stream>>>(qkv, ctx);
        // h2 = h + ctx @ W_o[l] + b_o[l]
        gemm_nn<<<dim3(D / 64, T / 64, 1), 256, 0, stream>>>(
            ctx, W_o + (long)l * D * D, b_o + (long)l * D, h, h2,
            D, D, D, D, 0, 0, 0, 1 | 2);
        // xl = ln2(h2)
        ln_kernel<<<T, 256, 0, stream>>>(h2, ln2_g + l * D, ln2_b + l * D, xl);
        // f = gelu(xl @ W_fc[l] + b_fc[l])
        gemm_nn<<<dim3(FF / 64, T / 64, 1), 256, 0, stream>>>(
            xl, W_fc + (long)l * D * FF, b_fc + (long)l * FF, nullptr, f,
            D, D, FF, FF, 0, 0, 0, 1 | 4);
        // h = h2 + f @ W_proj[l] + b_proj[l]
        gemm_nn<<<dim3(D / 64, T / 64, 1), 256, 0, stream>>>(
            f, W_proj + (long)l * FF * D, b_proj + (long)l * D, h2, h,
            FF, FF, D, D, 0, 0, 0, 1 | 2);
    }
}

// Round 3
// 5396.648 us; speedup vs baseline: 1.1805x; 1.1805x over previous
//
#include <hip/hip_runtime.h>
#include <hip/hip_bf16.h>
#include <math.h>

namespace {

constexpr int T = 1024;      // sequence length
constexpr int D = 768;       // model dim
constexpr int FF = 3072;     // ffn dim
constexpr int H = 12;        // heads
constexpr int HD = 64;       // head dim
constexpr int L = 12;        // layers
constexpr float SCALE = 0.125f;                 // 1/sqrt(64)

// ---------------- embedding: h0 = wte[ids] + wpe ----------------
__global__ void embed_kernel(const int* __restrict__ ids,
                             const float* __restrict__ wte,
                             const float* __restrict__ wpe,
                             float* __restrict__ h) {
    int i = blockIdx.x * blockDim.x + threadIdx.x;
    if (i >= T * D) return;
    int t = i / D, d = i % D;
    h[i] = wte[(long)ids[t] * D + d] + wpe[i];
}

// ---------------- layernorm over D=768, one row per block (256 thr) ----------------
__global__ __launch_bounds__(256)
void ln_kernel(const float* __restrict__ x, const float* __restrict__ g,
               const float* __restrict__ b, float* __restrict__ out) {
    int row = blockIdx.x, tid = threadIdx.x;
    const float* xr = x + (long)row * D;
    float v0 = xr[tid], v1 = xr[tid + 256], v2 = xr[tid + 512];
    __shared__ float red[4];
    __shared__ float share;
    float s = v0 + v1 + v2;
#pragma unroll
    for (int o = 32; o; o >>= 1) s += __shfl_down(s, o, 64);
    if ((tid & 63) == 0) red[tid >> 6] = s;
    __syncthreads();
    if (tid == 0) share = (red[0] + red[1] + red[2] + red[3]) * (1.0f / D);
    __syncthreads();
    float mu = share;
    float d0 = v0 - mu, d1 = v1 - mu, d2 = v2 - mu;
    float q = d0 * d0 + d1 * d1 + d2 * d2;
#pragma unroll
    for (int o = 32; o; o >>= 1) q += __shfl_down(q, o, 64);
    __syncthreads();   // protect red reuse
    if ((tid & 63) == 0) red[tid >> 6] = q;
    __syncthreads();
    if (tid == 0) share = rsqrtf((red[0] + red[1] + red[2] + red[3]) * (1.0f / D) + 1e-5f);
    __syncthreads();
    float rs = share;
    float* orow = out + (long)row * D;
    orow[tid]       = d0 * rs * g[tid]       + b[tid];
    orow[tid + 256] = d1 * rs * g[tid + 256] + b[tid + 256];
    orow[tid + 512] = d2 * rs * g[tid + 512] + b[tid + 512];
}

// ---------------- fp32 GEMM, split-K, partials out ----------------
// C_part[z][T][N] += A[T,K(chunk z)] @ B[K(chunk z),N]
// tile 128x64, 256 threads, 8x4 micro, BK=16, single-barrier double-buffer.
// lda == K, ldb == N. grid (N/64, T/128, splitK).
__global__ __launch_bounds__(256)
void gemm_nn(const float* __restrict__ A, const float* __restrict__ B,
             float* __restrict__ part, int N, int K, int splitK) {
    const int z = blockIdx.z;
    const int Kc = K / splitK;
    const int kb = z * Kc;
    const int row0 = blockIdx.y * 128, col0 = blockIdx.x * 64;
    __shared__ float As[2][16][132];   // [kk][m], pad 132
    __shared__ float Bs[2][16][68];    // [kk][n], pad 68
    const int tid = threadIdx.x;
    const int tx = tid & 15, ty = tid >> 4;
    const int ar = tid >> 1, ac = (tid & 1) * 8;   // A stage: row ar, cols ac..ac+7
    const int br = tid >> 4, bc = (tid & 15) * 4;  // B stage: row br, cols bc..bc+3
    const float* Arow = A + (long)(row0 + ar) * K + kb + ac;
    const float* Brow = B + (long)(kb + br) * N + col0 + bc;
    float acc[8][4] = {};

    // prologue: stage step 0 into buf 0
    {
        float4 a0 = *(const float4*)(Arow);
        float4 a1 = *(const float4*)(Arow + 4);
        float4 bv = *(const float4*)(Brow);
        As[0][ac + 0][ar] = a0.x; As[0][ac + 1][ar] = a0.y;
        As[0][ac + 2][ar] = a0.z; As[0][ac + 3][ar] = a0.w;
        As[0][ac + 4][ar] = a1.x; As[0][ac + 5][ar] = a1.y;
        As[0][ac + 6][ar] = a1.z; As[0][ac + 7][ar] = a1.w;
        *(float4*)&Bs[0][br][bc] = bv;
    }
    __syncthreads();

    const int nsteps = Kc >> 4;
    for (int s = 0; s < nsteps; s++) {
        const int buf = s & 1;
        float4 na0, na1, nbv;
        const bool has_next = (s + 1 < nsteps);
        if (has_next) {   // issue global loads early (latency hides under FMAs)
            na0 = *(const float4*)(Arow + (s + 1) * 16);
            na1 = *(const float4*)(Arow + (s + 1) * 16 + 4);
            nbv = *(const float4*)(Brow + (long)(s + 1) * 16 * N);
        }
#pragma unroll
        for (int kk = 0; kk < 16; kk++) {
            float4 aA = *(const float4*)&As[buf][kk][ty * 8];
            float4 aB = *(const float4*)&As[buf][kk][ty * 8 + 4];
            float4 bF = *(const float4*)&Bs[buf][kk][tx * 4];
            acc[0][0] += aA.x * bF.x; acc[0][1] += aA.x * bF.y; acc[0][2] += aA.x * bF.z; acc[0][3] += aA.x * bF.w;
            acc[1][0] += aA.y * bF.x; acc[1][1] += aA.y * bF.y; acc[1][2] += aA.y * bF.z; acc[1][3] += aA.y * bF.w;
            acc[2][0] += aA.z * bF.x; acc[2][1] += aA.z * bF.y; acc[2][2] += aA.z * bF.z; acc[2][3] += aA.z * bF.w;
            acc[3][0] += aA.w * bF.x; acc[3][1] += aA.w * bF.y; acc[3][2] += aA.w * bF.z; acc[3][3] += aA.w * bF.w;
            acc[4][0] += aB.x * bF.x; acc[4][1] += aB.x * bF.y; acc[4][2] += aB.x * bF.z; acc[4][3] += aB.x * bF.w;
            acc[5][0] += aB.y * bF.x; acc[5][1] += aB.y * bF.y; acc[5][2] += aB.y * bF.z; acc[5][3] += aB.y * bF.w;
            acc[6][0] += aB.z * bF.x; acc[6][1] += aB.z * bF.y; acc[6][2] += aB.z * bF.z; acc[6][3] += aB.z * bF.w;
            acc[7][0] += aB.w * bF.x; acc[7][1] += aB.w * bF.y; acc[7][2] += aB.w * bF.z; acc[7][3] += aB.w * bF.w;
        }
        if (has_next) {   // write next tile into the *other* buffer (read 2 iters ago)
            const int nb = buf ^ 1;
            As[nb][ac + 0][ar] = na0.x; As[nb][ac + 1][ar] = na0.y;
            As[nb][ac + 2][ar] = na0.z; As[nb][ac + 3][ar] = na0.w;
            As[nb][ac + 4][ar] = na1.x; As[nb][ac + 5][ar] = na1.y;
            As[nb][ac + 6][ar] = na1.z; As[nb][ac + 7][ar] = na1.w;
            *(float4*)&Bs[nb][br][bc] = nbv;
        }
        __syncthreads();
    }

    // write partials: part[z][row][col]
    float* dst = part + (long)z * T * N;
#pragma unroll
    for (int i = 0; i < 8; i++) {
        int r = row0 + ty * 8 + i;
        float4 v = {acc[i][0], acc[i][1], acc[i][2], acc[i][3]};
        *(float4*)(dst + (long)r * N + col0 + tx * 4) = v;
    }
}

// ---------------- split-K reduce + epilogue ----------------
// C = sum_z part[z] (+bias)(gelu)(+resid). flags: 1=bias, 2=resid, 4=gelu.
__global__ __launch_bounds__(256)
void reduce_splitk(const float* __restrict__ part, const float* __restrict__ bias,
                   const float* __restrict__ resid, float* __restrict__ C,
                   int N, int splitK, int flags) {
    long idx = ((long)blockIdx.x * 256 + threadIdx.x) * 4;
    if (idx >= (long)T * N) return;
    int c = (int)(idx % N);
    float4 s = *(const float4*)(part + idx);
    for (int z = 1; z < splitK; z++) {
        float4 p = *(const float4*)(part + (long)z * T * N + idx);
        s.x += p.x; s.y += p.y; s.z += p.z; s.w += p.w;
    }
    if (flags & 1) {
        s.x += bias[c]; s.y += bias[c + 1]; s.z += bias[c + 2]; s.w += bias[c + 3];
    }
    if (flags & 4) {
        float* v = (float*)&s;
#pragma unroll
        for (int j = 0; j < 4; j++) {
            float x = v[j];
            v[j] = 0.5f * x * (1.0f + tanhf(0.7978845608028654f * (x + 0.044715f * x * x * x)));
        }
    }
    if (flags & 2) {
        float4 rv = *(const float4*)(resid + idx);
        s.x += rv.x; s.y += rv.y; s.z += rv.z; s.w += rv.w;
    }
    *(float4*)(C + idx) = s;
}

// ---------------- fused flash attention (fp32, causal), 32 q-rows per block ----------------
__global__ __launch_bounds__(256)
void flash_attn(const float* __restrict__ qkv, float* __restrict__ ctx) {
    const int h = blockIdx.y;
    const int r0 = blockIdx.x * 32;
    const int tid = threadIdx.x;
    const int r = tid & 31;     // local q row (both phases)
    const int g = tid >> 5;     // group 0..7: c-group (scores) / d-group (PV)
    __shared__ float Qs[32][68];
    __shared__ float Ks[32][68];
    __shared__ float Vs[32][68];
    __shared__ float Ps[32][33];
    __shared__ float RedM[32][9];
    __shared__ float RedS[32][9];

    for (int idx = tid; idx < 512; idx += 256) {
        int rr = idx >> 4, c4 = (idx & 15) << 2;
        *(float4*)&Qs[rr][c4] =
            *(const float4*)(qkv + (long)(r0 + rr) * (3 * D) + h * HD + c4);
    }
    float m = -INFINITY, l = 0.f;
    float o[8] = {0, 0, 0, 0, 0, 0, 0, 0};
    const int rg = r0 + r;
    const int cbase = g * 4;

    for (int c0 = 0; c0 <= r0; c0 += 32) {
        __syncthreads();
        for (int idx = tid; idx < 512; idx += 256) {
            int rr = idx >> 4, c4 = (idx & 15) << 2;
            const float* src = qkv + (long)(c0 + rr) * (3 * D) + D + h * HD + c4;
            *(float4*)&Ks[rr][c4] = *(const float4*)src;
            *(float4*)&Vs[rr][c4] = *(const float4*)(src + D);
        }
        __syncthreads();
        float a0 = 0, a1 = 0, a2 = 0, a3 = 0;
#pragma unroll
        for (int d = 0; d < 64; d += 4) {
            float4 q4 = *(const float4*)&Qs[r][d];
            float4 k0 = *(const float4*)&Ks[cbase + 0][d];
            float4 k1 = *(const float4*)&Ks[cbase + 1][d];
            float4 k2 = *(const float4*)&Ks[cbase + 2][d];
            float4 k3 = *(const float4*)&Ks[cbase + 3][d];
            a0 += q4.x * k0.x + q4.y * k0.y + q4.z * k0.z + q4.w * k0.w;
            a1 += q4.x * k1.x + q4.y * k1.y + q4.z * k1.z + q4.w * k1.w;
            a2 += q4.x * k2.x + q4.y * k2.y + q4.z * k2.z + q4.w * k2.w;
            a3 += q4.x * k3.x + q4.y * k3.y + q4.z * k3.z + q4.w * k3.w;
        }
        float s0 = (c0 + cbase + 0 <= rg) ? a0 * SCALE : -INFINITY;
        float s1 = (c0 + cbase + 1 <= rg) ? a1 * SCALE : -INFINITY;
        float s2 = (c0 + cbase + 2 <= rg) ? a2 * SCALE : -INFINITY;
        float s3 = (c0 + cbase + 3 <= rg) ? a3 * SCALE : -INFINITY;
        RedM[r][g] = fmaxf(fmaxf(s0, s1), fmaxf(s2, s3));
        __syncthreads();
        float mn = m;
#pragma unroll
        for (int k = 0; k < 8; k++) mn = fmaxf(mn, RedM[r][k]);
        float alpha = expf(m - mn);
        float p0 = expf(s0 - mn), p1 = expf(s1 - mn);
        float p2 = expf(s2 - mn), p3 = expf(s3 - mn);
        Ps[r][cbase + 0] = p0; Ps[r][cbase + 1] = p1;
        Ps[r][cbase + 2] = p2; Ps[r][cbase + 3] = p3;
        RedS[r][g] = p0 + p1 + p2 + p3;
        __syncthreads();
        float ps = 0;
#pragma unroll
        for (int k = 0; k < 8; k++) ps += RedS[r][k];
        l = l * alpha + ps;
        m = mn;
#pragma unroll
        for (int j = 0; j < 8; j++) o[j] *= alpha;
        for (int c = 0; c < 32; c++) {
            float p = Ps[r][c];
            float4 v0 = *(const float4*)&Vs[c][g * 8];
            float4 v1 = *(const float4*)&Vs[c][g * 8 + 4];
            o[0] += p * v0.x; o[1] += p * v0.y; o[2] += p * v0.z; o[3] += p * v0.w;
            o[4] += p * v1.x; o[5] += p * v1.y; o[6] += p * v1.z; o[7] += p * v1.w;
        }
    }
    float inv = 1.0f / l;
    float4 w0 = {o[0] * inv, o[1] * inv, o[2] * inv, o[3] * inv};
    float4 w1 = {o[4] * inv, o[5] * inv, o[6] * inv, o[7] * inv};
    float* dst = ctx + (long)rg * D + h * HD + g * 8;
    *(float4*)dst = w0;
    *(float4*)(dst + 4) = w1;
}

// ---------------- probe: softmax rows S2 and T-1 per head, write 4 outputs ----------------
__global__ __launch_bounds__(256)
void probe_kernel(const float* __restrict__ qkv,
                  const int* __restrict__ Sp, const int* __restrict__ Sa1p,
                  const int* __restrict__ S2p,
                  float* __restrict__ out, int layer) {
    const int h = blockIdx.y;
    const int which = blockIdx.x;
    const int s = *Sp, sa1 = *Sa1p, s2 = *S2p;
    const int row = which ? (T - 1) : s2;
    const int tid = threadIdx.x;
    __shared__ float qrow[64];
    __shared__ float prob[T];
    __shared__ float red[4];
    __shared__ float bshare;
    if (tid < 64) qrow[tid] = qkv[(long)row * (3 * D) + h * HD + tid];
    __syncthreads();
    float mloc = -INFINITY;
    for (int j = tid; j <= row; j += 256) {
        const float* krow = qkv + (long)j * (3 * D) + D + h * HD;
        float acc = 0;
#pragma unroll
        for (int d = 0; d < 64; d += 4) {
            float4 kv = *(const float4*)(krow + d);
            acc += qrow[d] * kv.x + qrow[d + 1] * kv.y +
                   qrow[d + 2] * kv.z + qrow[d + 3] * kv.w;
        }
        acc *= SCALE;
        prob[j] = acc;
        mloc = fmaxf(mloc, acc);
    }
#pragma unroll
    for (int o = 32; o; o >>= 1) mloc = fmaxf(mloc, __shfl_down(mloc, o, 64));
    if ((tid & 63) == 0) red[tid >> 6] = mloc;
    __syncthreads();
    if (tid == 0) bshare = fmaxf(fmaxf(red[0], red[1]), fmaxf(red[2], red[3]));
    __syncthreads();
    float m = bshare;
    float ssum = 0;
    for (int j = tid; j <= row; j += 256) {
        float e = expf(prob[j] - m);
        prob[j] = e;
        ssum += e;
    }
#pragma unroll
    for (int o = 32; o; o >>= 1) ssum += __shfl_down(ssum, o, 64);
    __syncthreads();
    if ((tid & 63) == 0) red[tid >> 6] = ssum;
    __syncthreads();
    if (tid == 0) bshare = red[0] + red[1] + red[2] + red[3];
    __syncthreads();
    float inv = 1.0f / bshare;
    if (tid == 0) {
        if (which == 0) {
            out[0 * (L * H) + layer * H + h] = prob[s] * inv;
            out[1 * (L * H) + layer * H + h] = prob[sa1] * inv;
        } else {
            out[2 * (L * H) + layer * H + h] = prob[s2] * inv;
            out[3 * (L * H) + layer * H + h] = prob[s2] * inv;
        }
    }
}

}  // namespace

extern "C" void kernel_launch(void* const* d_in, const int* in_sizes, int n_in,
                              void* d_out, int out_size, void* d_ws, size_t ws_size,
                              hipStream_t stream) {
    const int*   ids    = (const int*)  d_in[0];
    const float* wte    = (const float*)d_in[2];
    const float* wpe    = (const float*)d_in[3];
    const float* ln1_g  = (const float*)d_in[4];
    const float* ln1_b  = (const float*)d_in[5];
    const float* W_qkv  = (const float*)d_in[6];
    const float* b_qkv  = (const float*)d_in[7];
    const float* W_o    = (const float*)d_in[8];
    const float* b_o    = (const float*)d_in[9];
    const float* ln2_g  = (const float*)d_in[10];
    const float* ln2_b  = (const float*)d_in[11];
    const float* W_fc   = (const float*)d_in[12];
    const float* b_fc   = (const float*)d_in[13];
    const float* W_proj = (const float*)d_in[14];
    const float* b_proj = (const float*)d_in[15];
    const int*   Sp     = (const int*)  d_in[16];
    const int*   Sa1p   = (const int*)  d_in[17];
    const int*   S2p    = (const int*)  d_in[18];
    float* out = (float*)d_out;

    float* ws   = (float*)d_ws;
    float* h    = ws;                      // T*D
    float* xl   = h    + (long)T * D;      // T*D
    float* h2   = xl   + (long)T * D;      // T*D
    float* qkv  = h2   + (long)T * D;      // T*3D
    float* ctx  = qkv  + (long)T * 3 * D;  // T*D
    float* f    = ctx  + (long)T * D;      // T*FF
    float* part = f    + (long)T * FF;     // T*6144 (max split partials)

    auto rblocks = [](long n) { return (int)((n / 4 + 255) / 256); };

    embed_kernel<<<(T * D + 255) / 256, 256, 0, stream>>>(ids, wte, wpe, h);

    for (int l = 0; l < L; l++) {
        // xl = ln1(h)
        ln_kernel<<<T, 256, 0, stream>>>(h, ln1_g + l * D, ln1_b + l * D, xl);
        // qkv = xl @ W_qkv[l] + b_qkv[l]   (split-K=2)
        gemm_nn<<<dim3(3 * D / 64, T / 128, 2), 256, 0, stream>>>(
            xl, W_qkv + (long)l * D * 3 * D, part, 3 * D, D, 2);
        reduce_splitk<<<rblocks((long)T * 3 * D), 256, 0, stream>>>(
            part, b_qkv + (long)l * 3 * D, nullptr, qkv, 3 * D, 2, 1);
        // probe outputs for this layer (needs only qkv)
        probe_kernel<<<dim3(2, H), 256, 0, stream>>>(qkv, Sp, Sa1p, S2p, out, l);

        if (l == L - 1) break;  // last layer: h_new unused

        // ctx = causal-softmax(QK^T*scale) @ V, fused
        flash_attn<<<dim3(T / 32, H), 256, 0, stream>>>(qkv, ctx);
        // h2 = h + ctx @ W_o[l] + b_o[l]   (split-K=4)
        gemm_nn<<<dim3(D / 64, T / 128, 4), 256, 0, stream>>>(
            ctx, W_o + (long)l * D * D, part, D, D, 4);
        reduce_splitk<<<rblocks((long)T * D), 256, 0, stream>>>(
            part, b_o + (long)l * D, h, h2, D, 4, 1 | 2);
        // xl = ln2(h2)
        ln_kernel<<<T, 256, 0, stream>>>(h2, ln2_g + l * D, ln2_b + l * D, xl);
        // f = gelu(xl @ W_fc[l] + b_fc[l])   (split-K=2)
        gemm_nn<<<dim3(FF / 64, T / 128, 2), 256, 0, stream>>>(
            xl, W_fc + (long)l * D * FF, part, FF, D, 2);
        reduce_splitk<<<rblocks((long)T * FF), 256, 0, stream>>>(
            part, b_fc + (long)l * FF, nullptr, f, FF, 2, 1 | 4);
        // h = h2 + f @ W_proj[l] + b_proj[l]   (split-K=8)
        gemm_nn<<<dim3(D / 64, T / 128, 8), 256, 0, stream>>>(
            f, W_proj + (long)l * FF * D, part, D, FF, 8);
        reduce_splitk<<<rblocks((long)T * D), 256, 0, stream>>>(
            part, b_proj + (long)l * D, h2, h, D, 8, 1 | 2);
    }
}

// Round 5
// 3258.918 us; speedup vs baseline: 1.9548x; 1.6560x over previous
//
#include <hip/hip_runtime.h>
#include <hip/hip_bf16.h>
#include <math.h>

namespace {

constexpr int T = 1024;      // sequence length
constexpr int D = 768;       // model dim
constexpr int FF = 3072;     // ffn dim
constexpr int H = 12;        // heads
constexpr int HD = 64;       // head dim
constexpr int L = 12;        // layers
constexpr float SCALE = 0.125f;                 // 1/sqrt(64)

typedef __attribute__((ext_vector_type(8))) short short8;
typedef __attribute__((ext_vector_type(4))) float floatx4;

__device__ inline unsigned short f2bf(float f) {
    __hip_bfloat16 h = __float2bfloat16(f);   // RNE
    return *reinterpret_cast<unsigned short*>(&h);
}

// ---------------- embedding: h0 = wte[ids] + wpe ----------------
__global__ void embed_kernel(const int* __restrict__ ids,
                             const float* __restrict__ wte,
                             const float* __restrict__ wpe,
                             float* __restrict__ h) {
    int i = blockIdx.x * blockDim.x + threadIdx.x;
    if (i >= T * D) return;
    int t = i / D, d = i % D;
    h[i] = wte[(long)ids[t] * D + d] + wpe[i];
}

// ---------------- layernorm over D=768, one row per block (256 thr) ----------------
__global__ __launch_bounds__(256)
void ln_kernel(const float* __restrict__ x, const float* __restrict__ g,
               const float* __restrict__ b, float* __restrict__ out) {
    int row = blockIdx.x, tid = threadIdx.x;
    const float* xr = x + (long)row * D;
    float v0 = xr[tid], v1 = xr[tid + 256], v2 = xr[tid + 512];
    __shared__ float red[4];
    __shared__ float share;
    float s = v0 + v1 + v2;
#pragma unroll
    for (int o = 32; o; o >>= 1) s += __shfl_down(s, o, 64);
    if ((tid & 63) == 0) red[tid >> 6] = s;
    __syncthreads();
    if (tid == 0) share = (red[0] + red[1] + red[2] + red[3]) * (1.0f / D);
    __syncthreads();
    float mu = share;
    float d0 = v0 - mu, d1 = v1 - mu, d2 = v2 - mu;
    float q = d0 * d0 + d1 * d1 + d2 * d2;
#pragma unroll
    for (int o = 32; o; o >>= 1) q += __shfl_down(q, o, 64);
    __syncthreads();
    if ((tid & 63) == 0) red[tid >> 6] = q;
    __syncthreads();
    if (tid == 0) share = rsqrtf((red[0] + red[1] + red[2] + red[3]) * (1.0f / D) + 1e-5f);
    __syncthreads();
    float rs = share;
    float* orow = out + (long)row * D;
    orow[tid]       = d0 * rs * g[tid]       + b[tid];
    orow[tid + 256] = d1 * rs * g[tid + 256] + b[tid + 256];
    orow[tid + 512] = d2 * rs * g[tid + 512] + b[tid + 512];
}

// ---------------- weight transpose+convert: WT[n][k] = bf16(W[k][n]) ----------------
// grid (N/32, K/32), block (32, 8)
__global__ __launch_bounds__(256)
void wconvert(const float* __restrict__ W, unsigned short* __restrict__ WT,
              int K, int N) {
    __shared__ float t[32][33];
    const int n0 = blockIdx.x * 32, k0 = blockIdx.y * 32;
    const int tx = threadIdx.x, ty = threadIdx.y;
#pragma unroll
    for (int i = 0; i < 4; i++)
        t[ty * 4 + i][tx] = W[(long)(k0 + ty * 4 + i) * N + n0 + tx];
    __syncthreads();
#pragma unroll
    for (int i = 0; i < 4; i++)
        WT[(long)(n0 + ty * 4 + i) * K + k0 + tx] = f2bf(t[tx][ty * 4 + i]);
}

// ---------------- bf16 MFMA GEMM, split-K, fp32 partials ----------------
// part[z] += A(fp32 M=T x K) @ BT(bf16 N x K)^T.  tile 64x64, BK=32,
// 4 waves each computing 32x32 via 2x2 mfma_f32_16x16x32_bf16 frags.
// Fragment-major LDS: lane l's 16B frag at linear offset -> zero conflicts.
// grid (N/64, T/64, splitK)
__global__ __launch_bounds__(256)
void gemm_bf16(const float* __restrict__ A, const unsigned short* __restrict__ BT,
               float* __restrict__ part, int N, int K, int splitK) {
    const int z = blockIdx.z;
    const int Kc = K / splitK;
    const int kb = z * Kc;
    const int row0 = blockIdx.y * 64, col0 = blockIdx.x * 64;
    const int tid = threadIdx.x;
    const int w = tid >> 6, lane = tid & 63;
    const int blk16 = tid >> 6;          // staging: which 16-row block (0..3)
    const int sl = tid & 63;             // staging lane

    __shared__ unsigned short As[2][4][64][8];   // [buf][m16][lane][8 bf16] = 4KB/buf
    __shared__ unsigned short Bs[2][4][64][8];

    // staging source pointers (thread-invariant strides)
    const float* Ap = A + (long)(row0 + blk16 * 16 + (sl & 15)) * K + kb + (sl >> 4) * 8;
    const unsigned short* Bp = BT + (long)(col0 + blk16 * 16 + (sl & 15)) * K + kb + (sl >> 4) * 8;

    floatx4 acc[2][2] = {};

    // prologue: stage k-step 0 into buf 0
    {
        float4 a0 = *(const float4*)(Ap);
        float4 a1 = *(const float4*)(Ap + 4);
        short8 bv = *(const short8*)(Bp);
        short8 av;
        av[0] = (short)f2bf(a0.x); av[1] = (short)f2bf(a0.y);
        av[2] = (short)f2bf(a0.z); av[3] = (short)f2bf(a0.w);
        av[4] = (short)f2bf(a1.x); av[5] = (short)f2bf(a1.y);
        av[6] = (short)f2bf(a1.z); av[7] = (short)f2bf(a1.w);
        *(short8*)&As[0][blk16][sl][0] = av;
        *(short8*)&Bs[0][blk16][sl][0] = bv;
    }
    __syncthreads();

    const int nsteps = Kc >> 5;   // BK=32
    for (int s = 0; s < nsteps; s++) {
        const int buf = s & 1;
        float4 na0, na1; short8 nbv;
        const bool has_next = (s + 1 < nsteps);
        if (has_next) {
            na0 = *(const float4*)(Ap + (s + 1) * 32);
            na1 = *(const float4*)(Ap + (s + 1) * 32 + 4);
            nbv = *(const short8*)(Bp + (s + 1) * 32);
        }
        // fragments (linear lane-major LDS -> conflict-free ds_read_b128)
        short8 af[2], bfr[2];
#pragma unroll
        for (int mi = 0; mi < 2; mi++)
            af[mi] = *(const short8*)&As[buf][(w & 1) * 2 + mi][lane][0];
#pragma unroll
        for (int ni = 0; ni < 2; ni++)
            bfr[ni] = *(const short8*)&Bs[buf][(w >> 1) * 2 + ni][lane][0];
#pragma unroll
        for (int mi = 0; mi < 2; mi++)
#pragma unroll
            for (int ni = 0; ni < 2; ni++)
                acc[mi][ni] = __builtin_amdgcn_mfma_f32_16x16x32_bf16(
                    af[mi], bfr[ni], acc[mi][ni], 0, 0, 0);
        if (has_next) {
            const int nb = buf ^ 1;
            short8 av;
            av[0] = (short)f2bf(na0.x); av[1] = (short)f2bf(na0.y);
            av[2] = (short)f2bf(na0.z); av[3] = (short)f2bf(na0.w);
            av[4] = (short)f2bf(na1.x); av[5] = (short)f2bf(na1.y);
            av[6] = (short)f2bf(na1.z); av[7] = (short)f2bf(na1.w);
            *(short8*)&As[nb][blk16][sl][0] = av;
            *(short8*)&Bs[nb][blk16][sl][0] = nbv;
        }
        __syncthreads();
    }

    // write fp32 partials: C/D layout col=lane&15, row=(lane>>4)*4+reg (m89)
    float* dst = part + (long)z * T * N;
#pragma unroll
    for (int mi = 0; mi < 2; mi++) {
        int rg = row0 + ((w & 1) * 2 + mi) * 16 + (lane >> 4) * 4;
#pragma unroll
        for (int ni = 0; ni < 2; ni++) {
            int cg = col0 + ((w >> 1) * 2 + ni) * 16 + (lane & 15);
#pragma unroll
            for (int r = 0; r < 4; r++)
                dst[(long)(rg + r) * N + cg] = acc[mi][ni][r];
        }
    }
}

// ---------------- split-K reduce + epilogue ----------------
// C = sum_z part[z] (+bias)(gelu)(+resid). flags: 1=bias, 2=resid, 4=gelu.
__global__ __launch_bounds__(256)
void reduce_splitk(const float* __restrict__ part, const float* __restrict__ bias,
                   const float* __restrict__ resid, float* __restrict__ C,
                   int N, int splitK, int flags) {
    long idx = ((long)blockIdx.x * 256 + threadIdx.x) * 4;
    if (idx >= (long)T * N) return;
    int c = (int)(idx % N);
    float4 s = *(const float4*)(part + idx);
    for (int z = 1; z < splitK; z++) {
        float4 p = *(const float4*)(part + (long)z * T * N + idx);
        s.x += p.x; s.y += p.y; s.z += p.z; s.w += p.w;
    }
    if (flags & 1) {
        s.x += bias[c]; s.y += bias[c + 1]; s.z += bias[c + 2]; s.w += bias[c + 3];
    }
    if (flags & 4) {
        float* v = (float*)&s;
#pragma unroll
        for (int j = 0; j < 4; j++) {
            float x = v[j];
            float zz = 0.7978845608028654f * (x + 0.044715f * x * x * x);
            // 0.5*(1+tanh(z)) == 1/(1+exp(-2z))  (exact identity)
            v[j] = x / (1.0f + __expf(-2.0f * zz));
        }
    }
    if (flags & 2) {
        float4 rv = *(const float4*)(resid + idx);
        s.x += rv.x; s.y += rv.y; s.z += rv.z; s.w += rv.w;
    }
    *(float4*)(C + idx) = s;
}

// ---------------- fused flash attention (fp32, causal), 32 q-rows per block ----------------
__global__ __launch_bounds__(256)
void flash_attn(const float* __restrict__ qkv, float* __restrict__ ctx) {
    const int h = blockIdx.y;
    const int r0 = blockIdx.x * 32;
    const int tid = threadIdx.x;
    const int r = tid & 31;
    const int g = tid >> 5;
    __shared__ float Qs[32][68];
    __shared__ float Ks[32][68];
    __shared__ float Vs[32][68];
    __shared__ float Ps[32][33];
    __shared__ float RedM[32][9];
    __shared__ float RedS[32][9];

    for (int idx = tid; idx < 512; idx += 256) {
        int rr = idx >> 4, c4 = (idx & 15) << 2;
        *(float4*)&Qs[rr][c4] =
            *(const float4*)(qkv + (long)(r0 + rr) * (3 * D) + h * HD + c4);
    }
    float m = -INFINITY, l = 0.f;
    float o[8] = {0, 0, 0, 0, 0, 0, 0, 0};
    const int rg = r0 + r;
    const int cbase = g * 4;

    for (int c0 = 0; c0 <= r0; c0 += 32) {
        __syncthreads();
        for (int idx = tid; idx < 512; idx += 256) {
            int rr = idx >> 4, c4 = (idx & 15) << 2;
            const float* src = qkv + (long)(c0 + rr) * (3 * D) + D + h * HD + c4;
            *(float4*)&Ks[rr][c4] = *(const float4*)src;
            *(float4*)&Vs[rr][c4] = *(const float4*)(src + D);
        }
        __syncthreads();
        float a0 = 0, a1 = 0, a2 = 0, a3 = 0;
#pragma unroll
        for (int d = 0; d < 64; d += 4) {
            float4 q4 = *(const float4*)&Qs[r][d];
            float4 k0 = *(const float4*)&Ks[cbase + 0][d];
            float4 k1 = *(const float4*)&Ks[cbase + 1][d];
            float4 k2 = *(const float4*)&Ks[cbase + 2][d];
            float4 k3 = *(const float4*)&Ks[cbase + 3][d];
            a0 += q4.x * k0.x + q4.y * k0.y + q4.z * k0.z + q4.w * k0.w;
            a1 += q4.x * k1.x + q4.y * k1.y + q4.z * k1.z + q4.w * k1.w;
            a2 += q4.x * k2.x + q4.y * k2.y + q4.z * k2.z + q4.w * k2.w;
            a3 += q4.x * k3.x + q4.y * k3.y + q4.z * k3.z + q4.w * k3.w;
        }
        float s0 = (c0 + cbase + 0 <= rg) ? a0 * SCALE : -INFINITY;
        float s1 = (c0 + cbase + 1 <= rg) ? a1 * SCALE : -INFINITY;
        float s2 = (c0 + cbase + 2 <= rg) ? a2 * SCALE : -INFINITY;
        float s3 = (c0 + cbase + 3 <= rg) ? a3 * SCALE : -INFINITY;
        RedM[r][g] = fmaxf(fmaxf(s0, s1), fmaxf(s2, s3));
        __syncthreads();
        float mn = m;
#pragma unroll
        for (int k = 0; k < 8; k++) mn = fmaxf(mn, RedM[r][k]);
        float alpha = expf(m - mn);
        float p0 = expf(s0 - mn), p1 = expf(s1 - mn);
        float p2 = expf(s2 - mn), p3 = expf(s3 - mn);
        Ps[r][cbase + 0] = p0; Ps[r][cbase + 1] = p1;
        Ps[r][cbase + 2] = p2; Ps[r][cbase + 3] = p3;
        RedS[r][g] = p0 + p1 + p2 + p3;
        __syncthreads();
        float ps = 0;
#pragma unroll
        for (int k = 0; k < 8; k++) ps += RedS[r][k];
        l = l * alpha + ps;
        m = mn;
#pragma unroll
        for (int j = 0; j < 8; j++) o[j] *= alpha;
        for (int c = 0; c < 32; c++) {
            float p = Ps[r][c];
            float4 v0 = *(const float4*)&Vs[c][g * 8];
            float4 v1 = *(const float4*)&Vs[c][g * 8 + 4];
            o[0] += p * v0.x; o[1] += p * v0.y; o[2] += p * v0.z; o[3] += p * v0.w;
            o[4] += p * v1.x; o[5] += p * v1.y; o[6] += p * v1.z; o[7] += p * v1.w;
        }
    }
    float inv = 1.0f / l;
    float4 w0 = {o[0] * inv, o[1] * inv, o[2] * inv, o[3] * inv};
    float4 w1 = {o[4] * inv, o[5] * inv, o[6] * inv, o[7] * inv};
    float* dst = ctx + (long)rg * D + h * HD + g * 8;
    *(float4*)dst = w0;
    *(float4*)(dst + 4) = w1;
}

// ---------------- probe: softmax rows S2 and T-1 per head, write 4 outputs ----------------
__global__ __launch_bounds__(256)
void probe_kernel(const float* __restrict__ qkv,
                  const int* __restrict__ Sp, const int* __restrict__ Sa1p,
                  const int* __restrict__ S2p,
                  float* __restrict__ out, int layer) {
    const int h = blockIdx.y;
    const int which = blockIdx.x;
    const int s = *Sp, sa1 = *Sa1p, s2 = *S2p;
    const int row = which ? (T - 1) : s2;
    const int tid = threadIdx.x;
    __shared__ float qrow[64];
    __shared__ float prob[T];
    __shared__ float red[4];
    __shared__ float bshare;
    if (tid < 64) qrow[tid] = qkv[(long)row * (3 * D) + h * HD + tid];
    __syncthreads();
    float mloc = -INFINITY;
    for (int j = tid; j <= row; j += 256) {
        const float* krow = qkv + (long)j * (3 * D) + D + h * HD;
        float acc = 0;
#pragma unroll
        for (int d = 0; d < 64; d += 4) {
            float4 kv = *(const float4*)(krow + d);
            acc += qrow[d] * kv.x + qrow[d + 1] * kv.y +
                   qrow[d + 2] * kv.z + qrow[d + 3] * kv.w;
        }
        acc *= SCALE;
        prob[j] = acc;
        mloc = fmaxf(mloc, acc);
    }
#pragma unroll
    for (int o = 32; o; o >>= 1) mloc = fmaxf(mloc, __shfl_down(mloc, o, 64));
    if ((tid & 63) == 0) red[tid >> 6] = mloc;
    __syncthreads();
    if (tid == 0) bshare = fmaxf(fmaxf(red[0], red[1]), fmaxf(red[2], red[3]));
    __syncthreads();
    float m = bshare;
    float ssum = 0;
    for (int j = tid; j <= row; j += 256) {
        float e = expf(prob[j] - m);
        prob[j] = e;
        ssum += e;
    }
#pragma unroll
    for (int o = 32; o; o >>= 1) ssum += __shfl_down(ssum, o, 64);
    __syncthreads();
    if ((tid & 63) == 0) red[tid >> 6] = ssum;
    __syncthreads();
    if (tid == 0) bshare = red[0] + red[1] + red[2] + red[3];
    __syncthreads();
    float inv = 1.0f / bshare;
    if (tid == 0) {
        if (which == 0) {
            out[0 * (L * H) + layer * H + h] = prob[s] * inv;
            out[1 * (L * H) + layer * H + h] = prob[sa1] * inv;
        } else {
            out[2 * (L * H) + layer * H + h] = prob[s2] * inv;
            out[3 * (L * H) + layer * H + h] = prob[s2] * inv;
        }
    }
}

}  // namespace

extern "C" void kernel_launch(void* const* d_in, const int* in_sizes, int n_in,
                              void* d_out, int out_size, void* d_ws, size_t ws_size,
                              hipStream_t stream) {
    const int*   ids    = (const int*)  d_in[0];
    const float* wte    = (const float*)d_in[2];
    const float* wpe    = (const float*)d_in[3];
    const float* ln1_g  = (const float*)d_in[4];
    const float* ln1_b  = (const float*)d_in[5];
    const float* W_qkv  = (const float*)d_in[6];
    const float* b_qkv  = (const float*)d_in[7];
    const float* W_o    = (const float*)d_in[8];
    const float* b_o    = (const float*)d_in[9];
    const float* ln2_g  = (const float*)d_in[10];
    const float* ln2_b  = (const float*)d_in[11];
    const float* W_fc   = (const float*)d_in[12];
    const float* b_fc   = (const float*)d_in[13];
    const float* W_proj = (const float*)d_in[14];
    const float* b_proj = (const float*)d_in[15];
    const int*   Sp     = (const int*)  d_in[16];
    const int*   Sa1p   = (const int*)  d_in[17];
    const int*   S2p    = (const int*)  d_in[18];
    float* out = (float*)d_out;

    float* ws   = (float*)d_ws;
    float* h    = ws;                      // T*D
    float* xl   = h    + (long)T * D;      // T*D
    float* h2   = xl   + (long)T * D;      // T*D
    float* qkv  = h2   + (long)T * D;      // T*3D
    float* ctx  = qkv  + (long)T * 3 * D;  // T*D
    float* f    = ctx  + (long)T * D;      // T*FF
    float* part = f    + (long)T * FF;     // T*6144 fp32 (max split partials)
    unsigned short* wt = (unsigned short*)(part + (long)T * 6144);  // max FF*D bf16

    auto rblocks = [](long n) { return (int)((n / 4 + 255) / 256); };

    embed_kernel<<<(T * D + 255) / 256, 256, 0, stream>>>(ids, wte, wpe, h);

    for (int l = 0; l < L; l++) {
        // xl = ln1(h)
        ln_kernel<<<T, 256, 0, stream>>>(h, ln1_g + l * D, ln1_b + l * D, xl);
        // qkv = xl @ W_qkv[l] + b_qkv[l]   (bf16 MFMA, split-K=2)
        wconvert<<<dim3(3 * D / 32, D / 32), dim3(32, 8), 0, stream>>>(
            W_qkv + (long)l * D * 3 * D, wt, D, 3 * D);
        gemm_bf16<<<dim3(3 * D / 64, T / 64, 2), 256, 0, stream>>>(
            xl, wt, part, 3 * D, D, 2);
        reduce_splitk<<<rblocks((long)T * 3 * D), 256, 0, stream>>>(
            part, b_qkv + (long)l * 3 * D, nullptr, qkv, 3 * D, 2, 1);
        // probe outputs for this layer (needs only qkv)
        probe_kernel<<<dim3(2, H), 256, 0, stream>>>(qkv, Sp, Sa1p, S2p, out, l);

        if (l == L - 1) break;  // last layer: h_new unused

        // ctx = causal-softmax(QK^T*scale) @ V, fused
        flash_attn<<<dim3(T / 32, H), 256, 0, stream>>>(qkv, ctx);
        // h2 = h + ctx @ W_o[l] + b_o[l]   (split-K=4)
        wconvert<<<dim3(D / 32, D / 32), dim3(32, 8), 0, stream>>>(
            W_o + (long)l * D * D, wt, D, D);
        gemm_bf16<<<dim3(D / 64, T / 64, 4), 256, 0, stream>>>(
            ctx, wt, part, D, D, 4);
        reduce_splitk<<<rblocks((long)T * D), 256, 0, stream>>>(
            part, b_o + (long)l * D, h, h2, D, 4, 1 | 2);
        // xl = ln2(h2)
        ln_kernel<<<T, 256, 0, stream>>>(h2, ln2_g + l * D, ln2_b + l * D, xl);
        // f = gelu(xl @ W_fc[l] + b_fc[l])   (split-K=2)
        wconvert<<<dim3(FF / 32, D / 32), dim3(32, 8), 0, stream>>>(
            W_fc + (long)l * D * FF, wt, D, FF);
        gemm_bf16<<<dim3(FF / 64, T / 64, 2), 256, 0, stream>>>(
            xl, wt, part, FF, D, 2);
        reduce_splitk<<<rblocks((long)T * FF), 256, 0, stream>>>(
            part, b_fc + (long)l * FF, nullptr, f, FF, 2, 1 | 4);
        // h = h2 + f @ W_proj[l] + b_proj[l]   (split-K=4)
        wconvert<<<dim3(D / 32, FF / 32), dim3(32, 8), 0, stream>>>(
            W_proj + (long)l * FF * D, wt, FF, D);
        gemm_bf16<<<dim3(D / 64, T / 64, 4), 256, 0, stream>>>(
            f, wt, part, D, FF, 4);
        reduce_splitk<<<rblocks((long)T * D), 256, 0, stream>>>(
            part, b_proj + (long)l * D, h2, h, D, 4, 1 | 2);
    }
}

// Round 6
// 2077.414 us; speedup vs baseline: 3.0666x; 1.5687x over previous
//
#include <hip/hip_runtime.h>
#include <hip/hip_bf16.h>
#include <math.h>

namespace {

constexpr int T = 1024;      // sequence length
constexpr int D = 768;       // model dim
constexpr int FF = 3072;     // ffn dim
constexpr int H = 12;        // heads
constexpr int HD = 64;       // head dim
constexpr int L = 12;        // layers
constexpr float SCALE = 0.125f;                 // 1/sqrt(64)

typedef __attribute__((ext_vector_type(8))) short short8;
typedef __attribute__((ext_vector_type(4))) float floatx4;

__device__ inline unsigned short f2bf(float f) {
    __hip_bfloat16 h = __float2bfloat16(f);   // RNE
    return *reinterpret_cast<unsigned short*>(&h);
}

// ---------------- embedding: h0 = wte[ids] + wpe ----------------
__global__ void embed_kernel(const int* __restrict__ ids,
                             const float* __restrict__ wte,
                             const float* __restrict__ wpe,
                             float* __restrict__ h) {
    int i = blockIdx.x * blockDim.x + threadIdx.x;
    if (i >= T * D) return;
    int t = i / D, d = i % D;
    h[i] = wte[(long)ids[t] * D + d] + wpe[i];
}

// ---------------- layernorm over D=768, one row per block (256 thr) ----------------
__global__ __launch_bounds__(256)
void ln_kernel(const float* __restrict__ x, const float* __restrict__ g,
               const float* __restrict__ b, float* __restrict__ out) {
    int row = blockIdx.x, tid = threadIdx.x;
    const float* xr = x + (long)row * D;
    float v0 = xr[tid], v1 = xr[tid + 256], v2 = xr[tid + 512];
    __shared__ float red[4];
    __shared__ float share;
    float s = v0 + v1 + v2;
#pragma unroll
    for (int o = 32; o; o >>= 1) s += __shfl_down(s, o, 64);
    if ((tid & 63) == 0) red[tid >> 6] = s;
    __syncthreads();
    if (tid == 0) share = (red[0] + red[1] + red[2] + red[3]) * (1.0f / D);
    __syncthreads();
    float mu = share;
    float d0 = v0 - mu, d1 = v1 - mu, d2 = v2 - mu;
    float q = d0 * d0 + d1 * d1 + d2 * d2;
#pragma unroll
    for (int o = 32; o; o >>= 1) q += __shfl_down(q, o, 64);
    __syncthreads();
    if ((tid & 63) == 0) red[tid >> 6] = q;
    __syncthreads();
    if (tid == 0) share = rsqrtf((red[0] + red[1] + red[2] + red[3]) * (1.0f / D) + 1e-5f);
    __syncthreads();
    float rs = share;
    float* orow = out + (long)row * D;
    orow[tid]       = d0 * rs * g[tid]       + b[tid];
    orow[tid + 256] = d1 * rs * g[tid + 256] + b[tid + 256];
    orow[tid + 512] = d2 * rs * g[tid + 512] + b[tid + 512];
}

// ---------------- weight transpose+convert: WT[n][k] = bf16(W[k][n]) ----------------
__global__ __launch_bounds__(256)
void wconvert(const float* __restrict__ W, unsigned short* __restrict__ WT,
              int K, int N) {
    __shared__ float t[32][33];
    const int n0 = blockIdx.x * 32, k0 = blockIdx.y * 32;
    const int tx = threadIdx.x, ty = threadIdx.y;
#pragma unroll
    for (int i = 0; i < 4; i++)
        t[ty * 4 + i][tx] = W[(long)(k0 + ty * 4 + i) * N + n0 + tx];
    __syncthreads();
#pragma unroll
    for (int i = 0; i < 4; i++)
        WT[(long)(n0 + ty * 4 + i) * K + k0 + tx] = f2bf(t[tx][ty * 4 + i]);
}

// ---------------- bf16 MFMA GEMM, split-K, fp32 partials ----------------
__global__ __launch_bounds__(256)
void gemm_bf16(const float* __restrict__ A, const unsigned short* __restrict__ BT,
               float* __restrict__ part, int N, int K, int splitK) {
    const int z = blockIdx.z;
    const int Kc = K / splitK;
    const int kb = z * Kc;
    const int row0 = blockIdx.y * 64, col0 = blockIdx.x * 64;
    const int tid = threadIdx.x;
    const int w = tid >> 6, lane = tid & 63;
    const int blk16 = tid >> 6;
    const int sl = tid & 63;

    __shared__ unsigned short As[2][4][64][8];
    __shared__ unsigned short Bs[2][4][64][8];

    const float* Ap = A + (long)(row0 + blk16 * 16 + (sl & 15)) * K + kb + (sl >> 4) * 8;
    const unsigned short* Bp = BT + (long)(col0 + blk16 * 16 + (sl & 15)) * K + kb + (sl >> 4) * 8;

    floatx4 acc[2][2] = {};

    {
        float4 a0 = *(const float4*)(Ap);
        float4 a1 = *(const float4*)(Ap + 4);
        short8 bv = *(const short8*)(Bp);
        short8 av;
        av[0] = (short)f2bf(a0.x); av[1] = (short)f2bf(a0.y);
        av[2] = (short)f2bf(a0.z); av[3] = (short)f2bf(a0.w);
        av[4] = (short)f2bf(a1.x); av[5] = (short)f2bf(a1.y);
        av[6] = (short)f2bf(a1.z); av[7] = (short)f2bf(a1.w);
        *(short8*)&As[0][blk16][sl][0] = av;
        *(short8*)&Bs[0][blk16][sl][0] = bv;
    }
    __syncthreads();

    const int nsteps = Kc >> 5;   // BK=32
    for (int s = 0; s < nsteps; s++) {
        const int buf = s & 1;
        float4 na0, na1; short8 nbv;
        const bool has_next = (s + 1 < nsteps);
        if (has_next) {
            na0 = *(const float4*)(Ap + (s + 1) * 32);
            na1 = *(const float4*)(Ap + (s + 1) * 32 + 4);
            nbv = *(const short8*)(Bp + (s + 1) * 32);
        }
        short8 af[2], bfr[2];
#pragma unroll
        for (int mi = 0; mi < 2; mi++)
            af[mi] = *(const short8*)&As[buf][(w & 1) * 2 + mi][lane][0];
#pragma unroll
        for (int ni = 0; ni < 2; ni++)
            bfr[ni] = *(const short8*)&Bs[buf][(w >> 1) * 2 + ni][lane][0];
#pragma unroll
        for (int mi = 0; mi < 2; mi++)
#pragma unroll
            for (int ni = 0; ni < 2; ni++)
                acc[mi][ni] = __builtin_amdgcn_mfma_f32_16x16x32_bf16(
                    af[mi], bfr[ni], acc[mi][ni], 0, 0, 0);
        if (has_next) {
            const int nb = buf ^ 1;
            short8 av;
            av[0] = (short)f2bf(na0.x); av[1] = (short)f2bf(na0.y);
            av[2] = (short)f2bf(na0.z); av[3] = (short)f2bf(na0.w);
            av[4] = (short)f2bf(na1.x); av[5] = (short)f2bf(na1.y);
            av[6] = (short)f2bf(na1.z); av[7] = (short)f2bf(na1.w);
            *(short8*)&As[nb][blk16][sl][0] = av;
            *(short8*)&Bs[nb][blk16][sl][0] = nbv;
        }
        __syncthreads();
    }

    float* dst = part + (long)z * T * N;
#pragma unroll
    for (int mi = 0; mi < 2; mi++) {
        int rg = row0 + ((w & 1) * 2 + mi) * 16 + (lane >> 4) * 4;
#pragma unroll
        for (int ni = 0; ni < 2; ni++) {
            int cg = col0 + ((w >> 1) * 2 + ni) * 16 + (lane & 15);
#pragma unroll
            for (int r = 0; r < 4; r++)
                dst[(long)(rg + r) * N + cg] = acc[mi][ni][r];
        }
    }
}

// ---------------- split-K reduce + epilogue ----------------
__global__ __launch_bounds__(256)
void reduce_splitk(const float* __restrict__ part, const float* __restrict__ bias,
                   const float* __restrict__ resid, float* __restrict__ C,
                   int N, int splitK, int flags) {
    long idx = ((long)blockIdx.x * 256 + threadIdx.x) * 4;
    if (idx >= (long)T * N) return;
    int c = (int)(idx % N);
    float4 s = *(const float4*)(part + idx);
    for (int z = 1; z < splitK; z++) {
        float4 p = *(const float4*)(part + (long)z * T * N + idx);
        s.x += p.x; s.y += p.y; s.z += p.z; s.w += p.w;
    }
    if (flags & 1) {
        s.x += bias[c]; s.y += bias[c + 1]; s.z += bias[c + 2]; s.w += bias[c + 3];
    }
    if (flags & 4) {
        float* v = (float*)&s;
#pragma unroll
        for (int j = 0; j < 4; j++) {
            float x = v[j];
            float zz = 0.7978845608028654f * (x + 0.044715f * x * x * x);
            v[j] = x / (1.0f + __expf(-2.0f * zz));
        }
    }
    if (flags & 2) {
        float4 rv = *(const float4*)(resid + idx);
        s.x += rv.x; s.y += rv.y; s.z += rv.z; s.w += rv.w;
    }
    *(float4*)(C + idx) = s;
}

// ---------------- MFMA flash attention (bf16 compute, fp32 softmax state) ----------------
// grid (T/64, H), 256 threads = 4 waves; wave w owns q rows q0+w*16..+15.
// S^T = K@Q^T per 64-col KV tile; per-lane online softmax (lane q = l&15);
// P via wave-private LDS into A-frag layout; PV with LDS-transposed V.
__global__ __launch_bounds__(256)
void flash_mfma(const float* __restrict__ qkv, float* __restrict__ ctx) {
    const int h = blockIdx.y;
    const int q0 = blockIdx.x * 64;
    const int tid = threadIdx.x;
    const int w = tid >> 6;
    const int l = tid & 63;
    const int lm = l & 15;
    const int g = l >> 4;

    __shared__ unsigned short Kl[64][72];        // [k][d] bf16, pad 72
    __shared__ unsigned short Vt[64][80];        // [d][k] bf16, pad 80 (16B-aligned rows)
    __shared__ unsigned short Pl[4][16][72];     // per-wave P^T scratch

    // Q fragments (B-operand layout: lane holds q-col lm, d-elems g*8..+8 per k-step)
    short8 qf[2];
    {
        const float* qp = qkv + (long)(q0 + w * 16 + lm) * (3 * D) + h * HD + g * 8;
#pragma unroll
        for (int ks = 0; ks < 2; ks++) {
            float4 x0 = *(const float4*)(qp + ks * 32);
            float4 x1 = *(const float4*)(qp + ks * 32 + 4);
            short8 v;
            v[0] = (short)f2bf(x0.x * SCALE); v[1] = (short)f2bf(x0.y * SCALE);
            v[2] = (short)f2bf(x0.z * SCALE); v[3] = (short)f2bf(x0.w * SCALE);
            v[4] = (short)f2bf(x1.x * SCALE); v[5] = (short)f2bf(x1.y * SCALE);
            v[6] = (short)f2bf(x1.z * SCALE); v[7] = (short)f2bf(x1.w * SCALE);
            qf[ks] = v;
        }
    }

    const int d8 = (tid & 7) * 8;       // staging: dim offset
    const int kp = (tid >> 3) * 2;      // staging: row pair

    float m = -INFINITY, lsum = 0.f;
    floatx4 o[4] = {};                  // o[fd][r]: q=g*4+r, d=fd*16+lm
    const int qw = q0 + w * 16;
    const int nt = blockIdx.x + 1;

    for (int t = 0; t < nt; t++) {
        const int c0 = t * 64;
        __syncthreads();   // previous tile's LDS reads complete
        {   // stage K row-major, V transposed
            const float* kr0 = qkv + (long)(c0 + kp) * (3 * D) + D + h * HD + d8;
            const float* kr1 = kr0 + 3 * D;
            float4 ka = *(const float4*)kr0, kb2 = *(const float4*)(kr0 + 4);
            float4 kc = *(const float4*)kr1, kd = *(const float4*)(kr1 + 4);
            short8 kv0, kv1;
            kv0[0] = (short)f2bf(ka.x);  kv0[1] = (short)f2bf(ka.y);
            kv0[2] = (short)f2bf(ka.z);  kv0[3] = (short)f2bf(ka.w);
            kv0[4] = (short)f2bf(kb2.x); kv0[5] = (short)f2bf(kb2.y);
            kv0[6] = (short)f2bf(kb2.z); kv0[7] = (short)f2bf(kb2.w);
            kv1[0] = (short)f2bf(kc.x);  kv1[1] = (short)f2bf(kc.y);
            kv1[2] = (short)f2bf(kc.z);  kv1[3] = (short)f2bf(kc.w);
            kv1[4] = (short)f2bf(kd.x);  kv1[5] = (short)f2bf(kd.y);
            kv1[6] = (short)f2bf(kd.z);  kv1[7] = (short)f2bf(kd.w);
            *(short8*)&Kl[kp][d8]     = kv0;
            *(short8*)&Kl[kp + 1][d8] = kv1;
            const float* vr0 = kr0 + D;
            const float* vr1 = kr1 + D;
            float4 va = *(const float4*)vr0, vb2 = *(const float4*)(vr0 + 4);
            float4 vc = *(const float4*)vr1, vd = *(const float4*)(vr1 + 4);
            float v0a[8] = {va.x, va.y, va.z, va.w, vb2.x, vb2.y, vb2.z, vb2.w};
            float v1a[8] = {vc.x, vc.y, vc.z, vc.w, vd.x, vd.y, vd.z, vd.w};
#pragma unroll
            for (int j = 0; j < 8; j++) {
                unsigned int pk = (unsigned)f2bf(v0a[j]) | ((unsigned)f2bf(v1a[j]) << 16);
                *(unsigned int*)&Vt[d8 + j][kp] = pk;
            }
        }
        __syncthreads();

        if (c0 > qw + 15) continue;   // wave fully above diagonal (barriers done)

        // S^T(64k x 16q) = K @ Q^T
        floatx4 st[4] = {};
#pragma unroll
        for (int ks = 0; ks < 2; ks++)
#pragma unroll
            for (int mt = 0; mt < 4; mt++) {
                short8 af = *(const short8*)&Kl[mt * 16 + lm][ks * 32 + g * 8];
                st[mt] = __builtin_amdgcn_mfma_f32_16x16x32_bf16(af, qf[ks], st[mt], 0, 0, 0);
            }

        // mask + online softmax; lane owns q = qw+lm, k-values c0+mt*16+g*4+r
        const int qg = qw + lm;
        if (c0 + 63 > qw) {
#pragma unroll
            for (int mt = 0; mt < 4; mt++)
#pragma unroll
                for (int r = 0; r < 4; r++)
                    if (c0 + mt * 16 + g * 4 + r > qg) st[mt][r] = -INFINITY;
        }
        float tmax = -INFINITY;
#pragma unroll
        for (int mt = 0; mt < 4; mt++)
#pragma unroll
            for (int r = 0; r < 4; r++) tmax = fmaxf(tmax, st[mt][r]);
        tmax = fmaxf(tmax, __shfl_xor(tmax, 16));
        tmax = fmaxf(tmax, __shfl_xor(tmax, 32));
        float mn = fmaxf(m, tmax);
        float alpha = __expf(m - mn);
        float psum = 0.f;
        unsigned short pb[16];
#pragma unroll
        for (int mt = 0; mt < 4; mt++)
#pragma unroll
            for (int r = 0; r < 4; r++) {
                float p = __expf(st[mt][r] - mn);
                psum += p;
                pb[mt * 4 + r] = f2bf(p);
            }
        lsum = lsum * alpha + psum;
        m = mn;
        // P^T -> wave-private LDS (A-frag source); DS ops are wave-in-order
#pragma unroll
        for (int mt = 0; mt < 4; mt++) {
            unsigned int p0 = (unsigned)pb[mt * 4 + 0] | ((unsigned)pb[mt * 4 + 1] << 16);
            unsigned int p1 = (unsigned)pb[mt * 4 + 2] | ((unsigned)pb[mt * 4 + 3] << 16);
            *(unsigned int*)&Pl[w][lm][mt * 16 + g * 4]     = p0;
            *(unsigned int*)&Pl[w][lm][mt * 16 + g * 4 + 2] = p1;
        }
        // rescale O by alpha of its q rows (alpha lives in lane q)
        float ar0 = __shfl(alpha, g * 4 + 0), ar1 = __shfl(alpha, g * 4 + 1);
        float ar2 = __shfl(alpha, g * 4 + 2), ar3 = __shfl(alpha, g * 4 + 3);
#pragma unroll
        for (int fd = 0; fd < 4; fd++) {
            o[fd][0] *= ar0; o[fd][1] *= ar1; o[fd][2] *= ar2; o[fd][3] *= ar3;
        }
        // PV: O(16q x 64d) += P(16x64) @ V(64x64)
#pragma unroll
        for (int ks = 0; ks < 2; ks++) {
            short8 pa = *(const short8*)&Pl[w][lm][ks * 32 + g * 8];
#pragma unroll
            for (int fd = 0; fd < 4; fd++) {
                short8 vb = *(const short8*)&Vt[fd * 16 + lm][ks * 32 + g * 8];
                o[fd] = __builtin_amdgcn_mfma_f32_16x16x32_bf16(pa, vb, o[fd], 0, 0, 0);
            }
        }
    }
    // merge partial l across the 4 dup lanes of each q, normalize, write
    float l2 = lsum + __shfl_xor(lsum, 16);
    float l4 = l2 + __shfl_xor(l2, 32);
    float linv = 1.0f / l4;
    float lr0 = __shfl(linv, g * 4 + 0), lr1 = __shfl(linv, g * 4 + 1);
    float lr2 = __shfl(linv, g * 4 + 2), lr3 = __shfl(linv, g * 4 + 3);
#pragma unroll
    for (int fd = 0; fd < 4; fd++) {
        float* cp = ctx + (long)(qw + g * 4) * D + h * HD + fd * 16 + lm;
        cp[0 * D] = o[fd][0] * lr0;
        cp[1 * D] = o[fd][1] * lr1;
        cp[2 * D] = o[fd][2] * lr2;
        cp[3 * D] = o[fd][3] * lr3;
    }
}

// ---------------- probe: softmax rows S2 and T-1 per head, write 4 outputs ----------------
__global__ __launch_bounds__(256)
void probe_kernel(const float* __restrict__ qkv,
                  const int* __restrict__ Sp, const int* __restrict__ Sa1p,
                  const int* __restrict__ S2p,
                  float* __restrict__ out, int layer) {
    const int h = blockIdx.y;
    const int which = blockIdx.x;
    const int s = *Sp, sa1 = *Sa1p, s2 = *S2p;
    const int row = which ? (T - 1) : s2;
    const int tid = threadIdx.x;
    __shared__ float qrow[64];
    __shared__ float prob[T];
    __shared__ float red[4];
    __shared__ float bshare;
    if (tid < 64) qrow[tid] = qkv[(long)row * (3 * D) + h * HD + tid];
    __syncthreads();
    float mloc = -INFINITY;
    for (int j = tid; j <= row; j += 256) {
        const float* krow = qkv + (long)j * (3 * D) + D + h * HD;
        float acc = 0;
#pragma unroll
        for (int d = 0; d < 64; d += 4) {
            float4 kv = *(const float4*)(krow + d);
            acc += qrow[d] * kv.x + qrow[d + 1] * kv.y +
                   qrow[d + 2] * kv.z + qrow[d + 3] * kv.w;
        }
        acc *= SCALE;
        prob[j] = acc;
        mloc = fmaxf(mloc, acc);
    }
#pragma unroll
    for (int o = 32; o; o >>= 1) mloc = fmaxf(mloc, __shfl_down(mloc, o, 64));
    if ((tid & 63) == 0) red[tid >> 6] = mloc;
    __syncthreads();
    if (tid == 0) bshare = fmaxf(fmaxf(red[0], red[1]), fmaxf(red[2], red[3]));
    __syncthreads();
    float m = bshare;
    float ssum = 0;
    for (int j = tid; j <= row; j += 256) {
        float e = expf(prob[j] - m);
        prob[j] = e;
        ssum += e;
    }
#pragma unroll
    for (int o = 32; o; o >>= 1) ssum += __shfl_down(ssum, o, 64);
    __syncthreads();
    if ((tid & 63) == 0) red[tid >> 6] = ssum;
    __syncthreads();
    if (tid == 0) bshare = red[0] + red[1] + red[2] + red[3];
    __syncthreads();
    float inv = 1.0f / bshare;
    if (tid == 0) {
        if (which == 0) {
            out[0 * (L * H) + layer * H + h] = prob[s] * inv;
            out[1 * (L * H) + layer * H + h] = prob[sa1] * inv;
        } else {
            out[2 * (L * H) + layer * H + h] = prob[s2] * inv;
            out[3 * (L * H) + layer * H + h] = prob[s2] * inv;
        }
    }
}

}  // namespace

extern "C" void kernel_launch(void* const* d_in, const int* in_sizes, int n_in,
                              void* d_out, int out_size, void* d_ws, size_t ws_size,
                              hipStream_t stream) {
    const int*   ids    = (const int*)  d_in[0];
    const float* wte    = (const float*)d_in[2];
    const float* wpe    = (const float*)d_in[3];
    const float* ln1_g  = (const float*)d_in[4];
    const float* ln1_b  = (const float*)d_in[5];
    const float* W_qkv  = (const float*)d_in[6];
    const float* b_qkv  = (const float*)d_in[7];
    const float* W_o    = (const float*)d_in[8];
    const float* b_o    = (const float*)d_in[9];
    const float* ln2_g  = (const float*)d_in[10];
    const float* ln2_b  = (const float*)d_in[11];
    const float* W_fc   = (const float*)d_in[12];
    const float* b_fc   = (const float*)d_in[13];
    const float* W_proj = (const float*)d_in[14];
    const float* b_proj = (const float*)d_in[15];
    const int*   Sp     = (const int*)  d_in[16];
    const int*   Sa1p   = (const int*)  d_in[17];
    const int*   S2p    = (const int*)  d_in[18];
    float* out = (float*)d_out;

    float* ws   = (float*)d_ws;
    float* h    = ws;                      // T*D
    float* xl   = h    + (long)T * D;      // T*D
    float* h2   = xl   + (long)T * D;      // T*D
    float* qkv  = h2   + (long)T * D;      // T*3D
    float* ctx  = qkv  + (long)T * 3 * D;  // T*D
    float* f    = ctx  + (long)T * D;      // T*FF
    float* part = f    + (long)T * FF;     // T*6144 fp32 (max split partials)
    unsigned short* wt = (unsigned short*)(part + (long)T * 6144);  // max FF*D bf16

    auto rblocks = [](long n) { return (int)((n / 4 + 255) / 256); };

    embed_kernel<<<(T * D + 255) / 256, 256, 0, stream>>>(ids, wte, wpe, h);

    for (int l = 0; l < L; l++) {
        // xl = ln1(h)
        ln_kernel<<<T, 256, 0, stream>>>(h, ln1_g + l * D, ln1_b + l * D, xl);
        // qkv = xl @ W_qkv[l] + b_qkv[l]   (bf16 MFMA, split-K=2)
        wconvert<<<dim3(3 * D / 32, D / 32), dim3(32, 8), 0, stream>>>(
            W_qkv + (long)l * D * 3 * D, wt, D, 3 * D);
        gemm_bf16<<<dim3(3 * D / 64, T / 64, 2), 256, 0, stream>>>(
            xl, wt, part, 3 * D, D, 2);
        reduce_splitk<<<rblocks((long)T * 3 * D), 256, 0, stream>>>(
            part, b_qkv + (long)l * 3 * D, nullptr, qkv, 3 * D, 2, 1);
        // probe outputs for this layer (needs only qkv; fp32 exact)
        probe_kernel<<<dim3(2, H), 256, 0, stream>>>(qkv, Sp, Sa1p, S2p, out, l);

        if (l == L - 1) break;  // last layer: h_new unused

        // ctx = causal-softmax(QK^T*scale) @ V, fused (bf16 MFMA)
        flash_mfma<<<dim3(T / 64, H), 256, 0, stream>>>(qkv, ctx);
        // h2 = h + ctx @ W_o[l] + b_o[l]   (split-K=4)
        wconvert<<<dim3(D / 32, D / 32), dim3(32, 8), 0, stream>>>(
            W_o + (long)l * D * D, wt, D, D);
        gemm_bf16<<<dim3(D / 64, T / 64, 4), 256, 0, stream>>>(
            ctx, wt, part, D, D, 4);
        reduce_splitk<<<rblocks((long)T * D), 256, 0, stream>>>(
            part, b_o + (long)l * D, h, h2, D, 4, 1 | 2);
        // xl = ln2(h2)
        ln_kernel<<<T, 256, 0, stream>>>(h2, ln2_g + l * D, ln2_b + l * D, xl);
        // f = gelu(xl @ W_fc[l] + b_fc[l])   (split-K=2)
        wconvert<<<dim3(FF / 32, D / 32), dim3(32, 8), 0, stream>>>(
            W_fc + (long)l * D * FF, wt, D, FF);
        gemm_bf16<<<dim3(FF / 64, T / 64, 2), 256, 0, stream>>>(
            xl, wt, part, FF, D, 2);
        reduce_splitk<<<rblocks((long)T * FF), 256, 0, stream>>>(
            part, b_fc + (long)l * FF, nullptr, f, FF, 2, 1 | 4);
        // h = h2 + f @ W_proj[l] + b_proj[l]   (split-K=4)
        wconvert<<<dim3(D / 32, FF / 32), dim3(32, 8), 0, stream>>>(
            W_proj + (long)l * FF * D, wt, FF, D);
        gemm_bf16<<<dim3(D / 64, T / 64, 4), 256, 0, stream>>>(
            f, wt, part, D, FF, 4);
        reduce_splitk<<<rblocks((long)T * D), 256, 0, stream>>>(
            part, b_proj + (long)l * D, h2, h, D, 4, 1 | 2);
    }
}

// Round 7
// 1839.562 us; speedup vs baseline: 3.4631x; 1.1293x over previous
//
#include <hip/hip_runtime.h>
#include <hip/hip_bf16.h>
#include <math.h>

namespace {

constexpr int T = 1024;      // sequence length
constexpr int D = 768;       // model dim
constexpr int FF = 3072;     // ffn dim
constexpr int H = 12;        // heads
constexpr int HD = 64;       // head dim
constexpr int L = 12;        // layers
constexpr float SCALE = 0.125f;                 // 1/sqrt(64)

typedef __attribute__((ext_vector_type(8))) short short8;
typedef __attribute__((ext_vector_type(4))) float floatx4;

__device__ inline unsigned short f2bf(float f) {
    __hip_bfloat16 h = __float2bfloat16(f);   // RNE
    return *reinterpret_cast<unsigned short*>(&h);
}

// ---------------- embedding: h0 = wte[ids] + wpe ----------------
__global__ void embed_kernel(const int* __restrict__ ids,
                             const float* __restrict__ wte,
                             const float* __restrict__ wpe,
                             float* __restrict__ h) {
    int i = blockIdx.x * blockDim.x + threadIdx.x;
    if (i >= T * D) return;
    int t = i / D, d = i % D;
    h[i] = wte[(long)ids[t] * D + d] + wpe[i];
}

// ---------------- layernorm over D=768, one row per block (256 thr) ----------------
__global__ __launch_bounds__(256)
void ln_kernel(const float* __restrict__ x, const float* __restrict__ g,
               const float* __restrict__ b, float* __restrict__ out) {
    int row = blockIdx.x, tid = threadIdx.x;
    const float* xr = x + (long)row * D;
    float v0 = xr[tid], v1 = xr[tid + 256], v2 = xr[tid + 512];
    __shared__ float red[4];
    __shared__ float share;
    float s = v0 + v1 + v2;
#pragma unroll
    for (int o = 32; o; o >>= 1) s += __shfl_down(s, o, 64);
    if ((tid & 63) == 0) red[tid >> 6] = s;
    __syncthreads();
    if (tid == 0) share = (red[0] + red[1] + red[2] + red[3]) * (1.0f / D);
    __syncthreads();
    float mu = share;
    float d0 = v0 - mu, d1 = v1 - mu, d2 = v2 - mu;
    float q = d0 * d0 + d1 * d1 + d2 * d2;
#pragma unroll
    for (int o = 32; o; o >>= 1) q += __shfl_down(q, o, 64);
    __syncthreads();
    if ((tid & 63) == 0) red[tid >> 6] = q;
    __syncthreads();
    if (tid == 0) share = rsqrtf((red[0] + red[1] + red[2] + red[3]) * (1.0f / D) + 1e-5f);
    __syncthreads();
    float rs = share;
    float* orow = out + (long)row * D;
    orow[tid]       = d0 * rs * g[tid]       + b[tid];
    orow[tid + 256] = d1 * rs * g[tid + 256] + b[tid + 256];
    orow[tid + 512] = d2 * rs * g[tid + 512] + b[tid + 512];
}

// ---------------- batched weight transpose+convert: WT[z][n][k] = bf16(W[z][k][n]) ----------------
// grid (N/32, K/32, L), block (32, 8)
__global__ __launch_bounds__(256)
void wconvert_b(const float* __restrict__ W, unsigned short* __restrict__ WT,
                int K, int N) {
    const int zl = blockIdx.z;
    W  += (long)zl * K * N;
    WT += (long)zl * N * K;
    __shared__ float t[32][33];
    const int n0 = blockIdx.x * 32, k0 = blockIdx.y * 32;
    const int tx = threadIdx.x, ty = threadIdx.y;
#pragma unroll
    for (int i = 0; i < 4; i++)
        t[ty * 4 + i][tx] = W[(long)(k0 + ty * 4 + i) * N + n0 + tx];
    __syncthreads();
#pragma unroll
    for (int i = 0; i < 4; i++)
        WT[(long)(n0 + ty * 4 + i) * K + k0 + tx] = f2bf(t[tx][ty * 4 + i]);
}

// ---------------- shared GEMM core macro-parts (64x64 tile, BK=32, 4 waves, 2x2 frags) ----------------
#define GEMM_CORE(KLEN)                                                                 \
    floatx4 acc[2][2] = {};                                                             \
    {                                                                                   \
        float4 a0 = *(const float4*)(Ap);                                               \
        float4 a1 = *(const float4*)(Ap + 4);                                           \
        short8 bv = *(const short8*)(Bp);                                               \
        short8 av;                                                                      \
        av[0] = (short)f2bf(a0.x); av[1] = (short)f2bf(a0.y);                           \
        av[2] = (short)f2bf(a0.z); av[3] = (short)f2bf(a0.w);                           \
        av[4] = (short)f2bf(a1.x); av[5] = (short)f2bf(a1.y);                           \
        av[6] = (short)f2bf(a1.z); av[7] = (short)f2bf(a1.w);                           \
        *(short8*)&As[0][blk16][sl][0] = av;                                            \
        *(short8*)&Bs[0][blk16][sl][0] = bv;                                            \
    }                                                                                   \
    __syncthreads();                                                                    \
    const int nsteps = (KLEN) >> 5;                                                     \
    for (int s = 0; s < nsteps; s++) {                                                  \
        const int buf = s & 1;                                                          \
        float4 na0, na1; short8 nbv;                                                    \
        const bool has_next = (s + 1 < nsteps);                                         \
        if (has_next) {                                                                 \
            na0 = *(const float4*)(Ap + (s + 1) * 32);                                  \
            na1 = *(const float4*)(Ap + (s + 1) * 32 + 4);                              \
            nbv = *(const short8*)(Bp + (s + 1) * 32);                                  \
        }                                                                               \
        short8 af[2], bfr[2];                                                           \
        _Pragma("unroll")                                                               \
        for (int mi = 0; mi < 2; mi++)                                                  \
            af[mi] = *(const short8*)&As[buf][(w & 1) * 2 + mi][lane][0];               \
        _Pragma("unroll")                                                               \
        for (int ni = 0; ni < 2; ni++)                                                  \
            bfr[ni] = *(const short8*)&Bs[buf][(w >> 1) * 2 + ni][lane][0];             \
        _Pragma("unroll")                                                               \
        for (int mi = 0; mi < 2; mi++)                                                  \
            _Pragma("unroll")                                                           \
            for (int ni = 0; ni < 2; ni++)                                              \
                acc[mi][ni] = __builtin_amdgcn_mfma_f32_16x16x32_bf16(                  \
                    af[mi], bfr[ni], acc[mi][ni], 0, 0, 0);                             \
        if (has_next) {                                                                 \
            const int nb = buf ^ 1;                                                     \
            short8 av;                                                                  \
            av[0] = (short)f2bf(na0.x); av[1] = (short)f2bf(na0.y);                     \
            av[2] = (short)f2bf(na0.z); av[3] = (short)f2bf(na0.w);                     \
            av[4] = (short)f2bf(na1.x); av[5] = (short)f2bf(na1.y);                     \
            av[6] = (short)f2bf(na1.z); av[7] = (short)f2bf(na1.w);                     \
            *(short8*)&As[nb][blk16][sl][0] = av;                                       \
            *(short8*)&Bs[nb][blk16][sl][0] = nbv;                                      \
        }                                                                               \
        __syncthreads();                                                                \
    }

// ---------------- bf16 MFMA GEMM, fused epilogue (no split-K) ----------------
// C = A(fp32 TxK) @ BT(bf16 NxK)^T + bias (, gelu). flags: 1=bias, 4=gelu
// grid (N/64, T/64)
__global__ __launch_bounds__(256)
void gemm_fused(const float* __restrict__ A, const unsigned short* __restrict__ BT,
                const float* __restrict__ bias, float* __restrict__ C,
                int N, int K, int flags) {
    const int row0 = blockIdx.y * 64, col0 = blockIdx.x * 64;
    const int tid = threadIdx.x;
    const int w = tid >> 6, lane = tid & 63;
    const int blk16 = tid >> 6;
    const int sl = tid & 63;
    __shared__ unsigned short As[2][4][64][8];
    __shared__ unsigned short Bs[2][4][64][8];
    const float* Ap = A + (long)(row0 + blk16 * 16 + (sl & 15)) * K + (sl >> 4) * 8;
    const unsigned short* Bp = BT + (long)(col0 + blk16 * 16 + (sl & 15)) * K + (sl >> 4) * 8;

    GEMM_CORE(K)

#pragma unroll
    for (int mi = 0; mi < 2; mi++) {
        int rg = row0 + ((w & 1) * 2 + mi) * 16 + (lane >> 4) * 4;
#pragma unroll
        for (int ni = 0; ni < 2; ni++) {
            int cg = col0 + ((w >> 1) * 2 + ni) * 16 + (lane & 15);
            float bv = (flags & 1) ? bias[cg] : 0.f;
#pragma unroll
            for (int r = 0; r < 4; r++) {
                float v = acc[mi][ni][r] + bv;
                if (flags & 4) {
                    float zz = 0.7978845608028654f * (v + 0.044715f * v * v * v);
                    v = v / (1.0f + __expf(-2.0f * zz));
                }
                C[(long)(rg + r) * N + cg] = v;
            }
        }
    }
}

// ---------------- bf16 MFMA GEMM, split-K, fp32 partials ----------------
// grid (N/64, T/64, splitK)
__global__ __launch_bounds__(256)
void gemm_bf16(const float* __restrict__ A, const unsigned short* __restrict__ BT,
               float* __restrict__ part, int N, int K, int splitK) {
    const int z = blockIdx.z;
    const int Kc = K / splitK;
    const int kb = z * Kc;
    const int row0 = blockIdx.y * 64, col0 = blockIdx.x * 64;
    const int tid = threadIdx.x;
    const int w = tid >> 6, lane = tid & 63;
    const int blk16 = tid >> 6;
    const int sl = tid & 63;
    __shared__ unsigned short As[2][4][64][8];
    __shared__ unsigned short Bs[2][4][64][8];
    const float* Ap = A + (long)(row0 + blk16 * 16 + (sl & 15)) * K + kb + (sl >> 4) * 8;
    const unsigned short* Bp = BT + (long)(col0 + blk16 * 16 + (sl & 15)) * K + kb + (sl >> 4) * 8;

    GEMM_CORE(Kc)

    float* dst = part + (long)z * T * N;
#pragma unroll
    for (int mi = 0; mi < 2; mi++) {
        int rg = row0 + ((w & 1) * 2 + mi) * 16 + (lane >> 4) * 4;
#pragma unroll
        for (int ni = 0; ni < 2; ni++) {
            int cg = col0 + ((w >> 1) * 2 + ni) * 16 + (lane & 15);
#pragma unroll
            for (int r = 0; r < 4; r++)
                dst[(long)(rg + r) * N + cg] = acc[mi][ni][r];
        }
    }
}

// ---------------- split-K reduce + epilogue ----------------
__global__ __launch_bounds__(256)
void reduce_splitk(const float* __restrict__ part, const float* __restrict__ bias,
                   const float* __restrict__ resid, float* __restrict__ C,
                   int N, int splitK, int flags) {
    long idx = ((long)blockIdx.x * 256 + threadIdx.x) * 4;
    if (idx >= (long)T * N) return;
    int c = (int)(idx % N);
    float4 s = *(const float4*)(part + idx);
    for (int z = 1; z < splitK; z++) {
        float4 p = *(const float4*)(part + (long)z * T * N + idx);
        s.x += p.x; s.y += p.y; s.z += p.z; s.w += p.w;
    }
    if (flags & 1) {
        s.x += bias[c]; s.y += bias[c + 1]; s.z += bias[c + 2]; s.w += bias[c + 3];
    }
    if (flags & 4) {
        float* v = (float*)&s;
#pragma unroll
        for (int j = 0; j < 4; j++) {
            float x = v[j];
            float zz = 0.7978845608028654f * (x + 0.044715f * x * x * x);
            v[j] = x / (1.0f + __expf(-2.0f * zz));
        }
    }
    if (flags & 2) {
        float4 rv = *(const float4*)(resid + idx);
        s.x += rv.x; s.y += rv.y; s.z += rv.z; s.w += rv.w;
    }
    *(float4*)(C + idx) = s;
}

// ---------------- MFMA flash attention (bf16 compute, fp32 softmax state) ----------------
// grid (T/64, H), 256 threads = 4 waves; wave w owns q rows q0+w*16..+15.
__global__ __launch_bounds__(256)
void flash_mfma(const float* __restrict__ qkv, float* __restrict__ ctx) {
    const int h = blockIdx.y;
    const int q0 = blockIdx.x * 64;
    const int tid = threadIdx.x;
    const int w = tid >> 6;
    const int l = tid & 63;
    const int lm = l & 15;
    const int g = l >> 4;

    __shared__ unsigned short Kl[64][72];
    __shared__ unsigned short Vt[64][80];
    __shared__ unsigned short Pl[4][16][72];

    short8 qf[2];
    {
        const float* qp = qkv + (long)(q0 + w * 16 + lm) * (3 * D) + h * HD + g * 8;
#pragma unroll
        for (int ks = 0; ks < 2; ks++) {
            float4 x0 = *(const float4*)(qp + ks * 32);
            float4 x1 = *(const float4*)(qp + ks * 32 + 4);
            short8 v;
            v[0] = (short)f2bf(x0.x * SCALE); v[1] = (short)f2bf(x0.y * SCALE);
            v[2] = (short)f2bf(x0.z * SCALE); v[3] = (short)f2bf(x0.w * SCALE);
            v[4] = (short)f2bf(x1.x * SCALE); v[5] = (short)f2bf(x1.y * SCALE);
            v[6] = (short)f2bf(x1.z * SCALE); v[7] = (short)f2bf(x1.w * SCALE);
            qf[ks] = v;
        }
    }

    const int d8 = (tid & 7) * 8;
    const int kp = (tid >> 3) * 2;

    float m = -INFINITY, lsum = 0.f;
    floatx4 o[4] = {};
    const int qw = q0 + w * 16;
    const int nt = blockIdx.x + 1;

    for (int t = 0; t < nt; t++) {
        const int c0 = t * 64;
        __syncthreads();
        {   // stage K row-major, V transposed
            const float* kr0 = qkv + (long)(c0 + kp) * (3 * D) + D + h * HD + d8;
            const float* kr1 = kr0 + 3 * D;
            float4 ka = *(const float4*)kr0, kb2 = *(const float4*)(kr0 + 4);
            float4 kc = *(const float4*)kr1, kd = *(const float4*)(kr1 + 4);
            short8 kv0, kv1;
            kv0[0] = (short)f2bf(ka.x);  kv0[1] = (short)f2bf(ka.y);
            kv0[2] = (short)f2bf(ka.z);  kv0[3] = (short)f2bf(ka.w);
            kv0[4] = (short)f2bf(kb2.x); kv0[5] = (short)f2bf(kb2.y);
            kv0[6] = (short)f2bf(kb2.z); kv0[7] = (short)f2bf(kb2.w);
            kv1[0] = (short)f2bf(kc.x);  kv1[1] = (short)f2bf(kc.y);
            kv1[2] = (short)f2bf(kc.z);  kv1[3] = (short)f2bf(kc.w);
            kv1[4] = (short)f2bf(kd.x);  kv1[5] = (short)f2bf(kd.y);
            kv1[6] = (short)f2bf(kd.z);  kv1[7] = (short)f2bf(kd.w);
            *(short8*)&Kl[kp][d8]     = kv0;
            *(short8*)&Kl[kp + 1][d8] = kv1;
            const float* vr0 = kr0 + D;
            const float* vr1 = kr1 + D;
            float4 va = *(const float4*)vr0, vb2 = *(const float4*)(vr0 + 4);
            float4 vc = *(const float4*)vr1, vd = *(const float4*)(vr1 + 4);
            float v0a[8] = {va.x, va.y, va.z, va.w, vb2.x, vb2.y, vb2.z, vb2.w};
            float v1a[8] = {vc.x, vc.y, vc.z, vc.w, vd.x, vd.y, vd.z, vd.w};
#pragma unroll
            for (int j = 0; j < 8; j++) {
                unsigned int pk = (unsigned)f2bf(v0a[j]) | ((unsigned)f2bf(v1a[j]) << 16);
                *(unsigned int*)&Vt[d8 + j][kp] = pk;
            }
        }
        __syncthreads();

        if (c0 > qw + 15) continue;

        floatx4 st[4] = {};
#pragma unroll
        for (int ks = 0; ks < 2; ks++)
#pragma unroll
            for (int mt = 0; mt < 4; mt++) {
                short8 af = *(const short8*)&Kl[mt * 16 + lm][ks * 32 + g * 8];
                st[mt] = __builtin_amdgcn_mfma_f32_16x16x32_bf16(af, qf[ks], st[mt], 0, 0, 0);
            }

        const int qg = qw + lm;
        if (c0 + 63 > qw) {
#pragma unroll
            for (int mt = 0; mt < 4; mt++)
#pragma unroll
                for (int r = 0; r < 4; r++)
                    if (c0 + mt * 16 + g * 4 + r > qg) st[mt][r] = -INFINITY;
        }
        float tmax = -INFINITY;
#pragma unroll
        for (int mt = 0; mt < 4; mt++)
#pragma unroll
            for (int r = 0; r < 4; r++) tmax = fmaxf(tmax, st[mt][r]);
        tmax = fmaxf(tmax, __shfl_xor(tmax, 16));
        tmax = fmaxf(tmax, __shfl_xor(tmax, 32));
        float mn = fmaxf(m, tmax);
        float alpha = __expf(m - mn);
        float psum = 0.f;
        unsigned short pb[16];
#pragma unroll
        for (int mt = 0; mt < 4; mt++)
#pragma unroll
            for (int r = 0; r < 4; r++) {
                float p = __expf(st[mt][r] - mn);
                psum += p;
                pb[mt * 4 + r] = f2bf(p);
            }
        lsum = lsum * alpha + psum;
        m = mn;
#pragma unroll
        for (int mt = 0; mt < 4; mt++) {
            unsigned int p0 = (unsigned)pb[mt * 4 + 0] | ((unsigned)pb[mt * 4 + 1] << 16);
            unsigned int p1 = (unsigned)pb[mt * 4 + 2] | ((unsigned)pb[mt * 4 + 3] << 16);
            *(unsigned int*)&Pl[w][lm][mt * 16 + g * 4]     = p0;
            *(unsigned int*)&Pl[w][lm][mt * 16 + g * 4 + 2] = p1;
        }
        float ar0 = __shfl(alpha, g * 4 + 0), ar1 = __shfl(alpha, g * 4 + 1);
        float ar2 = __shfl(alpha, g * 4 + 2), ar3 = __shfl(alpha, g * 4 + 3);
#pragma unroll
        for (int fd = 0; fd < 4; fd++) {
            o[fd][0] *= ar0; o[fd][1] *= ar1; o[fd][2] *= ar2; o[fd][3] *= ar3;
        }
#pragma unroll
        for (int ks = 0; ks < 2; ks++) {
            short8 pa = *(const short8*)&Pl[w][lm][ks * 32 + g * 8];
#pragma unroll
            for (int fd = 0; fd < 4; fd++) {
                short8 vb = *(const short8*)&Vt[fd * 16 + lm][ks * 32 + g * 8];
                o[fd] = __builtin_amdgcn_mfma_f32_16x16x32_bf16(pa, vb, o[fd], 0, 0, 0);
            }
        }
    }
    float l2 = lsum + __shfl_xor(lsum, 16);
    float l4 = l2 + __shfl_xor(l2, 32);
    float linv = 1.0f / l4;
    float lr0 = __shfl(linv, g * 4 + 0), lr1 = __shfl(linv, g * 4 + 1);
    float lr2 = __shfl(linv, g * 4 + 2), lr3 = __shfl(linv, g * 4 + 3);
#pragma unroll
    for (int fd = 0; fd < 4; fd++) {
        float* cp = ctx + (long)(qw + g * 4) * D + h * HD + fd * 16 + lm;
        cp[0 * D] = o[fd][0] * lr0;
        cp[1 * D] = o[fd][1] * lr1;
        cp[2 * D] = o[fd][2] * lr2;
        cp[3 * D] = o[fd][3] * lr3;
    }
}

// ---------------- probe: softmax rows S2 and T-1 per head, write 4 outputs ----------------
__global__ __launch_bounds__(256)
void probe_kernel(const float* __restrict__ qkv,
                  const int* __restrict__ Sp, const int* __restrict__ Sa1p,
                  const int* __restrict__ S2p,
                  float* __restrict__ out, int layer) {
    const int h = blockIdx.y;
    const int which = blockIdx.x;
    const int s = *Sp, sa1 = *Sa1p, s2 = *S2p;
    const int row = which ? (T - 1) : s2;
    const int tid = threadIdx.x;
    __shared__ float qrow[64];
    __shared__ float prob[T];
    __shared__ float red[4];
    __shared__ float bshare;
    if (tid < 64) qrow[tid] = qkv[(long)row * (3 * D) + h * HD + tid];
    __syncthreads();
    float mloc = -INFINITY;
    for (int j = tid; j <= row; j += 256) {
        const float* krow = qkv + (long)j * (3 * D) + D + h * HD;
        float acc = 0;
#pragma unroll
        for (int d = 0; d < 64; d += 4) {
            float4 kv = *(const float4*)(krow + d);
            acc += qrow[d] * kv.x + qrow[d + 1] * kv.y +
                   qrow[d + 2] * kv.z + qrow[d + 3] * kv.w;
        }
        acc *= SCALE;
        prob[j] = acc;
        mloc = fmaxf(mloc, acc);
    }
#pragma unroll
    for (int o = 32; o; o >>= 1) mloc = fmaxf(mloc, __shfl_down(mloc, o, 64));
    if ((tid & 63) == 0) red[tid >> 6] = mloc;
    __syncthreads();
    if (tid == 0) bshare = fmaxf(fmaxf(red[0], red[1]), fmaxf(red[2], red[3]));
    __syncthreads();
    float m = bshare;
    float ssum = 0;
    for (int j = tid; j <= row; j += 256) {
        float e = expf(prob[j] - m);
        prob[j] = e;
        ssum += e;
    }
#pragma unroll
    for (int o = 32; o; o >>= 1) ssum += __shfl_down(ssum, o, 64);
    __syncthreads();
    if ((tid & 63) == 0) red[tid >> 6] = ssum;
    __syncthreads();
    if (tid == 0) bshare = red[0] + red[1] + red[2] + red[3];
    __syncthreads();
    float inv = 1.0f / bshare;
    if (tid == 0) {
        if (which == 0) {
            out[0 * (L * H) + layer * H + h] = prob[s] * inv;
            out[1 * (L * H) + layer * H + h] = prob[sa1] * inv;
        } else {
            out[2 * (L * H) + layer * H + h] = prob[s2] * inv;
            out[3 * (L * H) + layer * H + h] = prob[s2] * inv;
        }
    }
}

}  // namespace

extern "C" void kernel_launch(void* const* d_in, const int* in_sizes, int n_in,
                              void* d_out, int out_size, void* d_ws, size_t ws_size,
                              hipStream_t stream) {
    const int*   ids    = (const int*)  d_in[0];
    const float* wte    = (const float*)d_in[2];
    const float* wpe    = (const float*)d_in[3];
    const float* ln1_g  = (const float*)d_in[4];
    const float* ln1_b  = (const float*)d_in[5];
    const float* W_qkv  = (const float*)d_in[6];
    const float* b_qkv  = (const float*)d_in[7];
    const float* W_o    = (const float*)d_in[8];
    const float* b_o    = (const float*)d_in[9];
    const float* ln2_g  = (const float*)d_in[10];
    const float* ln2_b  = (const float*)d_in[11];
    const float* W_fc   = (const float*)d_in[12];
    const float* b_fc   = (const float*)d_in[13];
    const float* W_proj = (const float*)d_in[14];
    const float* b_proj = (const float*)d_in[15];
    const int*   Sp     = (const int*)  d_in[16];
    const int*   Sa1p   = (const int*)  d_in[17];
    const int*   S2p    = (const int*)  d_in[18];
    float* out = (float*)d_out;

    float* ws   = (float*)d_ws;
    float* h    = ws;                      // T*D
    float* xl   = h    + (long)T * D;      // T*D
    float* h2   = xl   + (long)T * D;      // T*D
    float* qkv  = h2   + (long)T * D;      // T*3D
    float* ctx  = qkv  + (long)T * 3 * D;  // T*D
    float* f    = ctx  + (long)T * D;      // T*FF
    float* part = f    + (long)T * FF;     // 4*T*D fp32 (split partials)
    unsigned short* wt_qkv  = (unsigned short*)(part + 4L * T * D);
    unsigned short* wt_o    = wt_qkv  + (long)L * 3 * D * D;
    unsigned short* wt_fc   = wt_o    + (long)L * D * D;
    unsigned short* wt_proj = wt_fc   + (long)L * FF * D;
    // total ws: ~50MB activations + ~170MB bf16 weights (<618MB workspace)

    auto rblocks = [](long n) { return (int)((n / 4 + 255) / 256); };

    // upfront: embedding + ALL weight conversions (batched over layers, parallel)
    embed_kernel<<<(T * D + 255) / 256, 256, 0, stream>>>(ids, wte, wpe, h);
    wconvert_b<<<dim3(3 * D / 32, D / 32, L), dim3(32, 8), 0, stream>>>(W_qkv, wt_qkv, D, 3 * D);
    wconvert_b<<<dim3(D / 32, D / 32, L), dim3(32, 8), 0, stream>>>(W_o, wt_o, D, D);
    wconvert_b<<<dim3(FF / 32, D / 32, L), dim3(32, 8), 0, stream>>>(W_fc, wt_fc, D, FF);
    wconvert_b<<<dim3(D / 32, FF / 32, L), dim3(32, 8), 0, stream>>>(W_proj, wt_proj, FF, D);

    for (int l = 0; l < L; l++) {
        // xl = ln1(h)
        ln_kernel<<<T, 256, 0, stream>>>(h, ln1_g + l * D, ln1_b + l * D, xl);
        // qkv = xl @ W_qkv[l] + b_qkv[l]   (fused epilogue, 576 blocks)
        gemm_fused<<<dim3(3 * D / 64, T / 64), 256, 0, stream>>>(
            xl, wt_qkv + (long)l * 3 * D * D, b_qkv + (long)l * 3 * D, qkv, 3 * D, D, 1);
        // probe outputs for this layer (fp32 exact)
        probe_kernel<<<dim3(2, H), 256, 0, stream>>>(qkv, Sp, Sa1p, S2p, out, l);

        if (l == L - 1) break;  // last layer: h_new unused

        // ctx = causal-softmax(QK^T*scale) @ V, fused (bf16 MFMA)
        flash_mfma<<<dim3(T / 64, H), 256, 0, stream>>>(qkv, ctx);
        // h2 = h + ctx @ W_o[l] + b_o[l]   (split-K=4)
        gemm_bf16<<<dim3(D / 64, T / 64, 4), 256, 0, stream>>>(
            ctx, wt_o + (long)l * D * D, part, D, D, 4);
        reduce_splitk<<<rblocks((long)T * D), 256, 0, stream>>>(
            part, b_o + (long)l * D, h, h2, D, 4, 1 | 2);
        // xl = ln2(h2)
        ln_kernel<<<T, 256, 0, stream>>>(h2, ln2_g + l * D, ln2_b + l * D, xl);
        // f = gelu(xl @ W_fc[l] + b_fc[l])   (fused epilogue, 768 blocks)
        gemm_fused<<<dim3(FF / 64, T / 64), 256, 0, stream>>>(
            xl, wt_fc + (long)l * FF * D, b_fc + (long)l * FF, f, FF, D, 1 | 4);
        // h = h2 + f @ W_proj[l] + b_proj[l]   (split-K=4)
        gemm_bf16<<<dim3(D / 64, T / 64, 4), 256, 0, stream>>>(
            f, wt_proj + (long)l * D * FF, part, D, FF, 4);
        reduce_splitk<<<rblocks((long)T * D), 256, 0, stream>>>(
            part, b_proj + (long)l * D, h2, h, D, 4, 1 | 2);
    }
}

// Round 8
// 1461.178 us; speedup vs baseline: 4.3599x; 1.2590x over previous
//
#include <hip/hip_runtime.h>
#include <hip/hip_bf16.h>
#include <math.h>

namespace {

constexpr int T = 1024;      // sequence length
constexpr int D = 768;       // model dim
constexpr int FF = 3072;     // ffn dim
constexpr int H = 12;        // heads
constexpr int HD = 64;       // head dim
constexpr int L = 12;        // layers
constexpr float SCALE = 0.125f;                 // 1/sqrt(64), exact power of 2

typedef __attribute__((ext_vector_type(8))) short short8;
typedef __attribute__((ext_vector_type(4))) float floatx4;

__device__ inline unsigned short f2bf(float f) {
    __hip_bfloat16 h = __float2bfloat16(f);   // RNE
    return *reinterpret_cast<unsigned short*>(&h);
}

// ---------------- embedding: h0 = wte[ids] + wpe ----------------
__global__ void embed_kernel(const int* __restrict__ ids,
                             const float* __restrict__ wte,
                             const float* __restrict__ wpe,
                             float* __restrict__ h) {
    int i = blockIdx.x * blockDim.x + threadIdx.x;
    if (i >= T * D) return;
    int t = i / D, d = i % D;
    h[i] = wte[(long)ids[t] * D + d] + wpe[i];
}

// ---------------- layernorm (fp32 in, bf16 out), one row per block ----------------
__global__ __launch_bounds__(256)
void ln_kernel(const float* __restrict__ x, const float* __restrict__ g,
               const float* __restrict__ b, unsigned short* __restrict__ out) {
    int row = blockIdx.x, tid = threadIdx.x;
    const float* xr = x + (long)row * D;
    float v0 = xr[tid], v1 = xr[tid + 256], v2 = xr[tid + 512];
    __shared__ float red[4];
    __shared__ float share;
    float s = v0 + v1 + v2;
#pragma unroll
    for (int o = 32; o; o >>= 1) s += __shfl_down(s, o, 64);
    if ((tid & 63) == 0) red[tid >> 6] = s;
    __syncthreads();
    if (tid == 0) share = (red[0] + red[1] + red[2] + red[3]) * (1.0f / D);
    __syncthreads();
    float mu = share;
    float d0 = v0 - mu, d1 = v1 - mu, d2 = v2 - mu;
    float q = d0 * d0 + d1 * d1 + d2 * d2;
#pragma unroll
    for (int o = 32; o; o >>= 1) q += __shfl_down(q, o, 64);
    __syncthreads();
    if ((tid & 63) == 0) red[tid >> 6] = q;
    __syncthreads();
    if (tid == 0) share = rsqrtf((red[0] + red[1] + red[2] + red[3]) * (1.0f / D) + 1e-5f);
    __syncthreads();
    float rs = share;
    unsigned short* orow = out + (long)row * D;
    orow[tid]       = f2bf(d0 * rs * g[tid]       + b[tid]);
    orow[tid + 256] = f2bf(d1 * rs * g[tid + 256] + b[tid + 256]);
    orow[tid + 512] = f2bf(d2 * rs * g[tid + 512] + b[tid + 512]);
}

// ---------------- batched weight transpose+convert: WT[z][n][k] = bf16(W[z][k][n]) ----------------
__global__ __launch_bounds__(256)
void wconvert_b(const float* __restrict__ W, unsigned short* __restrict__ WT,
                int K, int N) {
    const int zl = blockIdx.z;
    W  += (long)zl * K * N;
    WT += (long)zl * N * K;
    __shared__ float t[32][33];
    const int n0 = blockIdx.x * 32, k0 = blockIdx.y * 32;
    const int tx = threadIdx.x, ty = threadIdx.y;
#pragma unroll
    for (int i = 0; i < 4; i++)
        t[ty * 4 + i][tx] = W[(long)(k0 + ty * 4 + i) * N + n0 + tx];
    __syncthreads();
#pragma unroll
    for (int i = 0; i < 4; i++)
        WT[(long)(n0 + ty * 4 + i) * K + k0 + tx] = f2bf(t[tx][ty * 4 + i]);
}

// ---------------- shared GEMM core (64x64 tile, BK=32, 4 waves, 2x2 frags, bf16 A&B) ----------------
#define GEMM_CORE(KLEN)                                                                 \
    floatx4 acc[2][2] = {};                                                             \
    {                                                                                   \
        *(short8*)&As[0][blk16][sl][0] = *(const short8*)(Ap);                          \
        *(short8*)&Bs[0][blk16][sl][0] = *(const short8*)(Bp);                          \
    }                                                                                   \
    __syncthreads();                                                                    \
    const int nsteps = (KLEN) >> 5;                                                     \
    for (int s = 0; s < nsteps; s++) {                                                  \
        const int buf = s & 1;                                                          \
        short8 nav, nbv;                                                                \
        const bool has_next = (s + 1 < nsteps);                                         \
        if (has_next) {                                                                 \
            nav = *(const short8*)(Ap + (s + 1) * 32);                                  \
            nbv = *(const short8*)(Bp + (s + 1) * 32);                                  \
        }                                                                               \
        short8 af[2], bfr[2];                                                           \
        _Pragma("unroll")                                                               \
        for (int mi = 0; mi < 2; mi++)                                                  \
            af[mi] = *(const short8*)&As[buf][(w & 1) * 2 + mi][lane][0];               \
        _Pragma("unroll")                                                               \
        for (int ni = 0; ni < 2; ni++)                                                  \
            bfr[ni] = *(const short8*)&Bs[buf][(w >> 1) * 2 + ni][lane][0];             \
        _Pragma("unroll")                                                               \
        for (int mi = 0; mi < 2; mi++)                                                  \
            _Pragma("unroll")                                                           \
            for (int ni = 0; ni < 2; ni++)                                              \
                acc[mi][ni] = __builtin_amdgcn_mfma_f32_16x16x32_bf16(                  \
                    af[mi], bfr[ni], acc[mi][ni], 0, 0, 0);                             \
        if (has_next) {                                                                 \
            const int nb = buf ^ 1;                                                     \
            *(short8*)&As[nb][blk16][sl][0] = nav;                                      \
            *(short8*)&Bs[nb][blk16][sl][0] = nbv;                                      \
        }                                                                               \
        __syncthreads();                                                                \
    }

// ---------------- bf16 MFMA GEMM, fused epilogue (no split-K) ----------------
// flags: 1=bias, 4=gelu, 8=also write fp32 C, 16=prescale cols<D by SCALE in bf16 out
// grid (N/64, T/64)
__global__ __launch_bounds__(256)
void gemm_fused(const unsigned short* __restrict__ A, const unsigned short* __restrict__ BT,
                const float* __restrict__ bias, float* __restrict__ C,
                unsigned short* __restrict__ Cb,
                int N, int K, int flags) {
    const int row0 = blockIdx.y * 64, col0 = blockIdx.x * 64;
    const int tid = threadIdx.x;
    const int w = tid >> 6, lane = tid & 63;
    const int blk16 = tid >> 6;
    const int sl = tid & 63;
    __shared__ unsigned short As[2][4][64][8];
    __shared__ unsigned short Bs[2][4][64][8];
    const unsigned short* Ap = A + (long)(row0 + blk16 * 16 + (sl & 15)) * K + (sl >> 4) * 8;
    const unsigned short* Bp = BT + (long)(col0 + blk16 * 16 + (sl & 15)) * K + (sl >> 4) * 8;

    GEMM_CORE(K)

#pragma unroll
    for (int mi = 0; mi < 2; mi++) {
        int rg = row0 + ((w & 1) * 2 + mi) * 16 + (lane >> 4) * 4;
#pragma unroll
        for (int ni = 0; ni < 2; ni++) {
            int cg = col0 + ((w >> 1) * 2 + ni) * 16 + (lane & 15);
            float bv = (flags & 1) ? bias[cg] : 0.f;
            float bscale = ((flags & 16) && cg < D) ? SCALE : 1.0f;
#pragma unroll
            for (int r = 0; r < 4; r++) {
                float v = acc[mi][ni][r] + bv;
                if (flags & 4) {
                    float zz = 0.7978845608028654f * (v + 0.044715f * v * v * v);
                    v = v / (1.0f + __expf(-2.0f * zz));
                }
                if (flags & 8) C[(long)(rg + r) * N + cg] = v;
                Cb[(long)(rg + r) * N + cg] = f2bf(v * bscale);
            }
        }
    }
}

// ---------------- bf16 MFMA GEMM, split-K, fp32 partials ----------------
// grid (N/64, T/64, splitK)
__global__ __launch_bounds__(256)
void gemm_bf16(const unsigned short* __restrict__ A, const unsigned short* __restrict__ BT,
               float* __restrict__ part, int N, int K, int splitK) {
    const int z = blockIdx.z;
    const int Kc = K / splitK;
    const int kb = z * Kc;
    const int row0 = blockIdx.y * 64, col0 = blockIdx.x * 64;
    const int tid = threadIdx.x;
    const int w = tid >> 6, lane = tid & 63;
    const int blk16 = tid >> 6;
    const int sl = tid & 63;
    __shared__ unsigned short As[2][4][64][8];
    __shared__ unsigned short Bs[2][4][64][8];
    const unsigned short* Ap = A + (long)(row0 + blk16 * 16 + (sl & 15)) * K + kb + (sl >> 4) * 8;
    const unsigned short* Bp = BT + (long)(col0 + blk16 * 16 + (sl & 15)) * K + kb + (sl >> 4) * 8;

    GEMM_CORE(Kc)

    float* dst = part + (long)z * T * N;
#pragma unroll
    for (int mi = 0; mi < 2; mi++) {
        int rg = row0 + ((w & 1) * 2 + mi) * 16 + (lane >> 4) * 4;
#pragma unroll
        for (int ni = 0; ni < 2; ni++) {
            int cg = col0 + ((w >> 1) * 2 + ni) * 16 + (lane & 15);
#pragma unroll
            for (int r = 0; r < 4; r++)
                dst[(long)(rg + r) * N + cg] = acc[mi][ni][r];
        }
    }
}

// ---------------- split-K reduce + residual + LayerNorm fused ----------------
// row per block: v = sum_z part[z][row] + bias + resid  -> Cres (fp32)
//                ln(v; g,b)                             -> Cln (bf16)
__global__ __launch_bounds__(256)
void reduce_ln(const float* __restrict__ part, const float* __restrict__ bias,
               const float* __restrict__ resid,
               const float* __restrict__ g, const float* __restrict__ b,
               float* __restrict__ Cres, unsigned short* __restrict__ Cln,
               int splitK) {
    const int row = blockIdx.x, tid = threadIdx.x;
    const int c0 = tid, c1 = tid + 256, c2 = tid + 512;
    const long rb = (long)row * D;
    float v0 = bias[c0] + resid[rb + c0];
    float v1 = bias[c1] + resid[rb + c1];
    float v2 = bias[c2] + resid[rb + c2];
    for (int z = 0; z < splitK; z++) {
        const float* p = part + (long)z * T * D + rb;
        v0 += p[c0]; v1 += p[c1]; v2 += p[c2];
    }
    float* crow = Cres + rb;
    crow[c0] = v0; crow[c1] = v1; crow[c2] = v2;
    __shared__ float red[4];
    __shared__ float share;
    float s = v0 + v1 + v2;
#pragma unroll
    for (int o = 32; o; o >>= 1) s += __shfl_down(s, o, 64);
    if ((tid & 63) == 0) red[tid >> 6] = s;
    __syncthreads();
    if (tid == 0) share = (red[0] + red[1] + red[2] + red[3]) * (1.0f / D);
    __syncthreads();
    float mu = share;
    float d0 = v0 - mu, d1 = v1 - mu, d2 = v2 - mu;
    float q = d0 * d0 + d1 * d1 + d2 * d2;
#pragma unroll
    for (int o = 32; o; o >>= 1) q += __shfl_down(q, o, 64);
    __syncthreads();
    if ((tid & 63) == 0) red[tid >> 6] = q;
    __syncthreads();
    if (tid == 0) share = rsqrtf((red[0] + red[1] + red[2] + red[3]) * (1.0f / D) + 1e-5f);
    __syncthreads();
    float rs = share;
    unsigned short* orow = Cln + rb;
    orow[c0] = f2bf(d0 * rs * g[c0] + b[c0]);
    orow[c1] = f2bf(d1 * rs * g[c1] + b[c1]);
    orow[c2] = f2bf(d2 * rs * g[c2] + b[c2]);
}

// ---------------- MFMA flash attention (bf16 in/out, fp32 softmax state) ----------------
// qkvb: T x 3D bf16 with Q pre-scaled by SCALE. grid (T/64, H), 4 waves.
__global__ __launch_bounds__(256)
void flash_mfma(const unsigned short* __restrict__ qkvb, unsigned short* __restrict__ ctxb) {
    const int h = blockIdx.y;
    const int q0 = blockIdx.x * 64;
    const int tid = threadIdx.x;
    const int w = tid >> 6;
    const int l = tid & 63;
    const int lm = l & 15;
    const int g = l >> 4;

    __shared__ unsigned short Kl[64][72];
    __shared__ unsigned short Vt[64][80];
    __shared__ unsigned short Pl[4][16][72];

    short8 qf[2];
    {
        const unsigned short* qp = qkvb + (long)(q0 + w * 16 + lm) * (3 * D) + h * HD + g * 8;
        qf[0] = *(const short8*)(qp);
        qf[1] = *(const short8*)(qp + 32);
    }

    const int d8 = (tid & 7) * 8;
    const int kp = (tid >> 3) * 2;

    float m = -INFINITY, lsum = 0.f;
    floatx4 o[4] = {};
    const int qw = q0 + w * 16;
    const int nt = blockIdx.x + 1;

    for (int t = 0; t < nt; t++) {
        const int c0 = t * 64;
        __syncthreads();
        {   // stage K row-major, V transposed (bf16 source, pure copies/repacks)
            const unsigned short* kr0 = qkvb + (long)(c0 + kp) * (3 * D) + D + h * HD + d8;
            const unsigned short* kr1 = kr0 + 3 * D;
            *(short8*)&Kl[kp][d8]     = *(const short8*)kr0;
            *(short8*)&Kl[kp + 1][d8] = *(const short8*)kr1;
            short8 va = *(const short8*)(kr0 + D);
            short8 vb = *(const short8*)(kr1 + D);
#pragma unroll
            for (int j = 0; j < 8; j++) {
                unsigned int pk = (unsigned)(unsigned short)va[j] |
                                  ((unsigned)(unsigned short)vb[j] << 16);
                *(unsigned int*)&Vt[d8 + j][kp] = pk;
            }
        }
        __syncthreads();

        if (c0 > qw + 15) continue;

        floatx4 st[4] = {};
#pragma unroll
        for (int ks = 0; ks < 2; ks++)
#pragma unroll
            for (int mt = 0; mt < 4; mt++) {
                short8 af = *(const short8*)&Kl[mt * 16 + lm][ks * 32 + g * 8];
                st[mt] = __builtin_amdgcn_mfma_f32_16x16x32_bf16(af, qf[ks], st[mt], 0, 0, 0);
            }

        const int qg = qw + lm;
        if (c0 + 63 > qw) {
#pragma unroll
            for (int mt = 0; mt < 4; mt++)
#pragma unroll
                for (int r = 0; r < 4; r++)
                    if (c0 + mt * 16 + g * 4 + r > qg) st[mt][r] = -INFINITY;
        }
        float tmax = -INFINITY;
#pragma unroll
        for (int mt = 0; mt < 4; mt++)
#pragma unroll
            for (int r = 0; r < 4; r++) tmax = fmaxf(tmax, st[mt][r]);
        tmax = fmaxf(tmax, __shfl_xor(tmax, 16));
        tmax = fmaxf(tmax, __shfl_xor(tmax, 32));
        float mn = fmaxf(m, tmax);
        float alpha = __expf(m - mn);
        float psum = 0.f;
        unsigned short pb[16];
#pragma unroll
        for (int mt = 0; mt < 4; mt++)
#pragma unroll
            for (int r = 0; r < 4; r++) {
                float p = __expf(st[mt][r] - mn);
                psum += p;
                pb[mt * 4 + r] = f2bf(p);
            }
        lsum = lsum * alpha + psum;
        m = mn;
#pragma unroll
        for (int mt = 0; mt < 4; mt++) {
            unsigned int p0 = (unsigned)pb[mt * 4 + 0] | ((unsigned)pb[mt * 4 + 1] << 16);
            unsigned int p1 = (unsigned)pb[mt * 4 + 2] | ((unsigned)pb[mt * 4 + 3] << 16);
            *(unsigned int*)&Pl[w][lm][mt * 16 + g * 4]     = p0;
            *(unsigned int*)&Pl[w][lm][mt * 16 + g * 4 + 2] = p1;
        }
        float ar0 = __shfl(alpha, g * 4 + 0), ar1 = __shfl(alpha, g * 4 + 1);
        float ar2 = __shfl(alpha, g * 4 + 2), ar3 = __shfl(alpha, g * 4 + 3);
#pragma unroll
        for (int fd = 0; fd < 4; fd++) {
            o[fd][0] *= ar0; o[fd][1] *= ar1; o[fd][2] *= ar2; o[fd][3] *= ar3;
        }
#pragma unroll
        for (int ks = 0; ks < 2; ks++) {
            short8 pa = *(const short8*)&Pl[w][lm][ks * 32 + g * 8];
#pragma unroll
            for (int fd = 0; fd < 4; fd++) {
                short8 vb = *(const short8*)&Vt[fd * 16 + lm][ks * 32 + g * 8];
                o[fd] = __builtin_amdgcn_mfma_f32_16x16x32_bf16(pa, vb, o[fd], 0, 0, 0);
            }
        }
    }
    float l2 = lsum + __shfl_xor(lsum, 16);
    float l4 = l2 + __shfl_xor(l2, 32);
    float linv = 1.0f / l4;
    float lr0 = __shfl(linv, g * 4 + 0), lr1 = __shfl(linv, g * 4 + 1);
    float lr2 = __shfl(linv, g * 4 + 2), lr3 = __shfl(linv, g * 4 + 3);
#pragma unroll
    for (int fd = 0; fd < 4; fd++) {
        unsigned short* cp = ctxb + (long)(qw + g * 4) * D + h * HD + fd * 16 + lm;
        cp[0 * D] = f2bf(o[fd][0] * lr0);
        cp[1 * D] = f2bf(o[fd][1] * lr1);
        cp[2 * D] = f2bf(o[fd][2] * lr2);
        cp[3 * D] = f2bf(o[fd][3] * lr3);
    }
}

// ---------------- probe: softmax rows S2 and T-1 per head (fp32 qkv, exact) ----------------
__global__ __launch_bounds__(256)
void probe_kernel(const float* __restrict__ qkv,
                  const int* __restrict__ Sp, const int* __restrict__ Sa1p,
                  const int* __restrict__ S2p,
                  float* __restrict__ out, int layer) {
    const int h = blockIdx.y;
    const int which = blockIdx.x;
    const int s = *Sp, sa1 = *Sa1p, s2 = *S2p;
    const int row = which ? (T - 1) : s2;
    const int tid = threadIdx.x;
    __shared__ float qrow[64];
    __shared__ float prob[T];
    __shared__ float red[4];
    __shared__ float bshare;
    if (tid < 64) qrow[tid] = qkv[(long)row * (3 * D) + h * HD + tid];
    __syncthreads();
    float mloc = -INFINITY;
    for (int j = tid; j <= row; j += 256) {
        const float* krow = qkv + (long)j * (3 * D) + D + h * HD;
        float acc = 0;
#pragma unroll
        for (int d = 0; d < 64; d += 4) {
            float4 kv = *(const float4*)(krow + d);
            acc += qrow[d] * kv.x + qrow[d + 1] * kv.y +
                   qrow[d + 2] * kv.z + qrow[d + 3] * kv.w;
        }
        acc *= SCALE;
        prob[j] = acc;
        mloc = fmaxf(mloc, acc);
    }
#pragma unroll
    for (int o = 32; o; o >>= 1) mloc = fmaxf(mloc, __shfl_down(mloc, o, 64));
    if ((tid & 63) == 0) red[tid >> 6] = mloc;
    __syncthreads();
    if (tid == 0) bshare = fmaxf(fmaxf(red[0], red[1]), fmaxf(red[2], red[3]));
    __syncthreads();
    float m = bshare;
    float ssum = 0;
    for (int j = tid; j <= row; j += 256) {
        float e = expf(prob[j] - m);
        prob[j] = e;
        ssum += e;
    }
#pragma unroll
    for (int o = 32; o; o >>= 1) ssum += __shfl_down(ssum, o, 64);
    __syncthreads();
    if ((tid & 63) == 0) red[tid >> 6] = ssum;
    __syncthreads();
    if (tid == 0) bshare = red[0] + red[1] + red[2] + red[3];
    __syncthreads();
    float inv = 1.0f / bshare;
    if (tid == 0) {
        if (which == 0) {
            out[0 * (L * H) + layer * H + h] = prob[s] * inv;
            out[1 * (L * H) + layer * H + h] = prob[sa1] * inv;
        } else {
            out[2 * (L * H) + layer * H + h] = prob[s2] * inv;
            out[3 * (L * H) + layer * H + h] = prob[s2] * inv;
        }
    }
}

}  // namespace

extern "C" void kernel_launch(void* const* d_in, const int* in_sizes, int n_in,
                              void* d_out, int out_size, void* d_ws, size_t ws_size,
                              hipStream_t stream) {
    const int*   ids    = (const int*)  d_in[0];
    const float* wte    = (const float*)d_in[2];
    const float* wpe    = (const float*)d_in[3];
    const float* ln1_g  = (const float*)d_in[4];
    const float* ln1_b  = (const float*)d_in[5];
    const float* W_qkv  = (const float*)d_in[6];
    const float* b_qkv  = (const float*)d_in[7];
    const float* W_o    = (const float*)d_in[8];
    const float* b_o    = (const float*)d_in[9];
    const float* ln2_g  = (const float*)d_in[10];
    const float* ln2_b  = (const float*)d_in[11];
    const float* W_fc   = (const float*)d_in[12];
    const float* b_fc   = (const float*)d_in[13];
    const float* W_proj = (const float*)d_in[14];
    const float* b_proj = (const float*)d_in[15];
    const int*   Sp     = (const int*)  d_in[16];
    const int*   Sa1p   = (const int*)  d_in[17];
    const int*   S2p    = (const int*)  d_in[18];
    float* out = (float*)d_out;

    float* ws   = (float*)d_ws;
    float* h    = ws;                      // T*D fp32 residual
    float* h2   = h   + (long)T * D;       // T*D fp32
    float* qkv  = h2  + (long)T * D;       // T*3D fp32 (probe)
    float* part = qkv + (long)T * 3 * D;   // 4*T*D fp32 split partials
    unsigned short* xl   = (unsigned short*)(part + 4L * T * D);   // T*D bf16 (LN out, reused)
    unsigned short* qkvb = xl   + (long)T * D;                     // T*3D bf16 (Q pre-scaled)
    unsigned short* ctxb = qkvb + (long)T * 3 * D;                 // T*D bf16
    unsigned short* fb   = ctxb + (long)T * D;                     // T*FF bf16
    unsigned short* wt_qkv  = fb      + (long)T * FF;
    unsigned short* wt_o    = wt_qkv  + (long)L * 3 * D * D;
    unsigned short* wt_fc   = wt_o    + (long)L * D * D;
    unsigned short* wt_proj = wt_fc   + (long)L * D * FF;
    // total ws ≈ 37MB fp32 + 13MB act bf16 + 170MB weights bf16 < 618MB

    // upfront: embedding + ALL weight conversions (parallel, batched over layers)
    embed_kernel<<<(T * D + 255) / 256, 256, 0, stream>>>(ids, wte, wpe, h);
    wconvert_b<<<dim3(3 * D / 32, D / 32, L), dim3(32, 8), 0, stream>>>(W_qkv, wt_qkv, D, 3 * D);
    wconvert_b<<<dim3(D / 32, D / 32, L), dim3(32, 8), 0, stream>>>(W_o, wt_o, D, D);
    wconvert_b<<<dim3(FF / 32, D / 32, L), dim3(32, 8), 0, stream>>>(W_fc, wt_fc, D, FF);
    wconvert_b<<<dim3(D / 32, FF / 32, L), dim3(32, 8), 0, stream>>>(W_proj, wt_proj, FF, D);
    // layer-0 ln1 (subsequent LNs are fused into reduce_ln)
    ln_kernel<<<T, 256, 0, stream>>>(h, ln1_g, ln1_b, xl);

    for (int l = 0; l < L; l++) {
        // qkv = xl @ W_qkv[l] + b_qkv[l] -> fp32 (probe) + bf16 w/ Q*SCALE (flash)
        gemm_fused<<<dim3(3 * D / 64, T / 64), 256, 0, stream>>>(
            xl, wt_qkv + (long)l * 3 * D * D, b_qkv + (long)l * 3 * D,
            qkv, qkvb, 3 * D, D, 1 | 8 | 16);
        probe_kernel<<<dim3(2, H), 256, 0, stream>>>(qkv, Sp, Sa1p, S2p, out, l);

        if (l == L - 1) break;  // last layer: h_new unused

        // ctx = causal-softmax(QK^T) @ V  (bf16 in/out)
        flash_mfma<<<dim3(T / 64, H), 256, 0, stream>>>(qkvb, ctxb);
        // h2 = h + ctx @ W_o + b_o ; xl = ln2(h2)
        gemm_bf16<<<dim3(D / 64, T / 64, 4), 256, 0, stream>>>(
            ctxb, wt_o + (long)l * D * D, part, D, D, 4);
        reduce_ln<<<T, 256, 0, stream>>>(
            part, b_o + (long)l * D, h, ln2_g + l * D, ln2_b + l * D, h2, xl, 4);
        // f = gelu(xl @ W_fc + b_fc)  (bf16 out)
        gemm_fused<<<dim3(FF / 64, T / 64), 256, 0, stream>>>(
            xl, wt_fc + (long)l * D * FF, b_fc + (long)l * FF,
            nullptr, fb, FF, D, 1 | 4);
        // h = h2 + f @ W_proj + b_proj ; xl = ln1_{l+1}(h)
        gemm_bf16<<<dim3(D / 64, T / 64, 4), 256, 0, stream>>>(
            fb, wt_proj + (long)l * D * FF, part, D, FF, 4);
        reduce_ln<<<T, 256, 0, stream>>>(
            part, b_proj + (long)l * D, h2, ln1_g + (l + 1) * D, ln1_b + (l + 1) * D, h, xl, 4);
    }
}